// Round 1
// baseline (552.850 us; speedup 1.0000x reference)
//
#include <hip/hip_runtime.h>
#include <hip/hip_bf16.h>
#include <math.h>

#define N_NODES 50000
#define N_EDGES 1600000
#define IN_FEAT 256
#define HIDDEN 128
#define N_CLASSES 16
#define NCHUNK 49          // ceil(50000/1024)

// ---------------------------------------------------------------------------
// Graph preprocessing: build CSR by destination each call (ws is re-poisoned)
// ---------------------------------------------------------------------------

__global__ void zero_deg(int* __restrict__ deg_cnt) {
    int i = blockIdx.x * blockDim.x + threadIdx.x;
    if (i < N_NODES) deg_cnt[i] = 0;
}

__global__ void count_deg(const int* __restrict__ dst, int* __restrict__ deg_cnt) {
    int i = blockIdx.x * blockDim.x + threadIdx.x;
    if (i < N_EDGES) atomicAdd(&deg_cnt[dst[i]], 1);
}

__global__ void compute_dis(const int* __restrict__ deg_cnt, float* __restrict__ dis) {
    int i = blockIdx.x * blockDim.x + threadIdx.x;
    if (i < N_NODES) dis[i] = 1.0f / sqrtf((float)(deg_cnt[i] + 1)); // +1 self loop
}

// chunk=1024 elements per block (256 thr x 4)
__global__ __launch_bounds__(256) void scan_chunk(const int* __restrict__ cnt,
                                                  int* __restrict__ excl,
                                                  int* __restrict__ sums) {
    __shared__ int lds[256];
    int t = threadIdx.x;
    int base = blockIdx.x * 1024 + t * 4;
    int v[4];
#pragma unroll
    for (int j = 0; j < 4; ++j) {
        int i = base + j;
        v[j] = (i < N_NODES) ? cnt[i] : 0;
    }
    int tsum = v[0] + v[1] + v[2] + v[3];
    lds[t] = tsum;
    __syncthreads();
    for (int off = 1; off < 256; off <<= 1) {
        int x = (t >= off) ? lds[t - off] : 0;
        __syncthreads();
        lds[t] += x;
        __syncthreads();
    }
    if (t == 255) sums[blockIdx.x] = lds[255];
    int run = lds[t] - tsum; // exclusive prefix of this thread's 4 elements
#pragma unroll
    for (int j = 0; j < 4; ++j) {
        int i = base + j;
        if (i < N_NODES) excl[i] = run;
        run += v[j];
    }
}

__global__ void scan_sums(int* __restrict__ sums) {
    int t = threadIdx.x; // 64 threads, one wave
    int v = (t < NCHUNK) ? sums[t] : 0;
    int orig = v;
    for (int off = 1; off < 64; off <<= 1) {
        int x = __shfl_up(v, off);
        if (t >= off) v += x;
    }
    if (t < NCHUNK) sums[t] = v - orig; // exclusive chunk base
}

__global__ void finalize_rs(const int* __restrict__ excl, const int* __restrict__ sums,
                            int* __restrict__ row_start, int* __restrict__ cursor) {
    int i = blockIdx.x * blockDim.x + threadIdx.x;
    if (i < N_NODES) {
        int rs = excl[i] + sums[i >> 10];
        row_start[i] = rs;
        cursor[i] = rs;
    } else if (i == N_NODES) {
        row_start[N_NODES] = N_EDGES;
    }
}

__global__ void fill_csr(const int* __restrict__ src, const int* __restrict__ dst,
                         int* __restrict__ cursor, int* __restrict__ csr_src) {
    int i = blockIdx.x * blockDim.x + threadIdx.x;
    if (i < N_EDGES) {
        int pos = atomicAdd(&cursor[dst[i]], 1);
        csr_src[pos] = src[i];
    }
}

// ---------------------------------------------------------------------------
// GEMM1: g1[i][:] = dis[i] * (x[i][:] @ W1)      [50000x256 @ 256x128]
// fp32 LDS-tiled. Block: 256 thr, tile 64 rows x 128 cols, BK=16.
// ---------------------------------------------------------------------------
#define BM 64
#define BN 128
#define BK 16

__global__ __launch_bounds__(256) void gemm1_scale(const float* __restrict__ x,
                                                   const float* __restrict__ W1,
                                                   const float* __restrict__ dis,
                                                   float* __restrict__ g1) {
    __shared__ float As[BK][68];  // A tile transposed [k][row], padded (+4) for write conflicts
    __shared__ float Bs[BK][BN];
    int tid = threadIdx.x;
    int block_row = blockIdx.x * BM;
    int c4 = (tid & 31) * 4;  // col base (4 cols)
    int r8 = (tid >> 5) * 8;  // row base (8 rows)
    float acc[8][4] = {};

    int a_row = tid >> 2;       // 0..63
    int a_k = (tid & 3) * 4;    // 0,4,8,12
    int b_k = tid >> 5;         // 0..7 (and +8)
    int b_c = (tid & 31) * 4;

    for (int k0 = 0; k0 < IN_FEAT; k0 += BK) {
        int grow = block_row + a_row;
        float4 av = make_float4(0.f, 0.f, 0.f, 0.f);
        if (grow < N_NODES) av = *(const float4*)&x[(size_t)grow * IN_FEAT + k0 + a_k];
        float4 bv0 = *(const float4*)&W1[(size_t)(k0 + b_k) * HIDDEN + b_c];
        float4 bv1 = *(const float4*)&W1[(size_t)(k0 + b_k + 8) * HIDDEN + b_c];
        __syncthreads();
        As[a_k + 0][a_row] = av.x;
        As[a_k + 1][a_row] = av.y;
        As[a_k + 2][a_row] = av.z;
        As[a_k + 3][a_row] = av.w;
        *(float4*)&Bs[b_k][b_c] = bv0;
        *(float4*)&Bs[b_k + 8][b_c] = bv1;
        __syncthreads();
#pragma unroll
        for (int kk = 0; kk < BK; ++kk) {
            float4 b = *(float4*)&Bs[kk][c4];
            float4 a0 = *(float4*)&As[kk][r8];
            float4 a1 = *(float4*)&As[kk][r8 + 4];
            float a[8] = {a0.x, a0.y, a0.z, a0.w, a1.x, a1.y, a1.z, a1.w};
            float bb[4] = {b.x, b.y, b.z, b.w};
#pragma unroll
            for (int j = 0; j < 8; ++j)
#pragma unroll
                for (int i = 0; i < 4; ++i) acc[j][i] += a[j] * bb[i];
        }
    }
#pragma unroll
    for (int j = 0; j < 8; ++j) {
        int row = block_row + r8 + j;
        if (row < N_NODES) {
            float dv = dis[row];
            float4 o = make_float4(acc[j][0] * dv, acc[j][1] * dv, acc[j][2] * dv, acc[j][3] * dv);
            *(float4*)&g1[(size_t)row * HIDDEN + c4] = o;
        }
    }
}

// ---------------------------------------------------------------------------
// Aggregation 1 + bias + ReLU. One wave per node, float2 per lane (128 feats).
// r[dst][:] = relu( dis[dst]*(g1[dst] + sum_{src} g1[src]) + b1 )
// ---------------------------------------------------------------------------
__global__ __launch_bounds__(256) void agg1_relu(const float* __restrict__ g1,
                                                 const int* __restrict__ row_start,
                                                 const int* __restrict__ csr_src,
                                                 const float* __restrict__ dis,
                                                 const float* __restrict__ b1,
                                                 float* __restrict__ r) {
    int wave = threadIdx.x >> 6;
    int lane = threadIdx.x & 63;
    int node = blockIdx.x * 4 + wave;  // 12500*4 == 50000 exactly
    int f = lane * 2;
    float2 acc = *(const float2*)&g1[(size_t)node * HIDDEN + f];  // self loop term
    int e0 = row_start[node], e1 = row_start[node + 1];
    for (int e = e0; e < e1; ++e) {
        int s = csr_src[e];
        float2 v = *(const float2*)&g1[(size_t)s * HIDDEN + f];
        acc.x += v.x;
        acc.y += v.y;
    }
    float dv = dis[node];
    float2 bb = *(const float2*)&b1[f];
    float ox = fmaxf(fmaf(dv, acc.x, bb.x), 0.f);
    float oy = fmaxf(fmaf(dv, acc.y, bb.y), 0.f);
    *(float2*)&r[(size_t)node * HIDDEN + f] = make_float2(ox, oy);
}

// ---------------------------------------------------------------------------
// GEMM2: g2[i][:] = dis[i] * (r[i][:] @ W2)      [50000x128 @ 128x16]
// 16 lanes per node, W2 staged in LDS.
// ---------------------------------------------------------------------------
__global__ __launch_bounds__(256) void gemm2_scale(const float* __restrict__ r,
                                                   const float* __restrict__ W2,
                                                   const float* __restrict__ dis,
                                                   float* __restrict__ g2) {
    __shared__ float w2s[HIDDEN * N_CLASSES];
    int tid = threadIdx.x;
    for (int i = tid; i < HIDDEN * N_CLASSES; i += 256) w2s[i] = W2[i];
    __syncthreads();
    int node = blockIdx.x * 16 + (tid >> 4);  // 3125*16 == 50000 exactly
    int c = tid & 15;
    const float* rr = &r[(size_t)node * HIDDEN];
    float acc = 0.f;
#pragma unroll
    for (int k4 = 0; k4 < HIDDEN / 4; ++k4) {
        float4 rv = *(const float4*)&rr[k4 * 4];
        acc = fmaf(rv.x, w2s[(k4 * 4 + 0) * 16 + c], acc);
        acc = fmaf(rv.y, w2s[(k4 * 4 + 1) * 16 + c], acc);
        acc = fmaf(rv.z, w2s[(k4 * 4 + 2) * 16 + c], acc);
        acc = fmaf(rv.w, w2s[(k4 * 4 + 3) * 16 + c], acc);
    }
    g2[(size_t)node * N_CLASSES + c] = dis[node] * acc;
}

// ---------------------------------------------------------------------------
// Aggregation 2 + bias + logits + softmax. 16 lanes per node.
// ---------------------------------------------------------------------------
__global__ __launch_bounds__(256) void agg2_softmax(const float* __restrict__ g2,
                                                    const int* __restrict__ row_start,
                                                    const int* __restrict__ csr_src,
                                                    const float* __restrict__ dis,
                                                    const float* __restrict__ b2,
                                                    float* __restrict__ out) {
    int tid = threadIdx.x;
    int node = blockIdx.x * 16 + (tid >> 4);
    int c = tid & 15;
    float acc = g2[(size_t)node * N_CLASSES + c];
    int e0 = row_start[node], e1 = row_start[node + 1];
    for (int e = e0; e < e1; ++e) {
        int s = csr_src[e];
        acc += g2[(size_t)s * N_CLASSES + c];
    }
    float logit = fmaf(dis[node], acc, b2[c]);
    out[(size_t)node * N_CLASSES + c] = logit;
    // softmax across the 16-lane group (xor masks 1..8 stay inside the group)
    float m = logit;
    for (int off = 8; off; off >>= 1) m = fmaxf(m, __shfl_xor(m, off));
    float ex = expf(logit - m);
    float s = ex;
    for (int off = 8; off; off >>= 1) s += __shfl_xor(s, off);
    out[(size_t)N_NODES * N_CLASSES + (size_t)node * N_CLASSES + c] = ex / s;
}

// ---------------------------------------------------------------------------

extern "C" void kernel_launch(void* const* d_in, const int* in_sizes, int n_in,
                              void* d_out, int out_size, void* d_ws, size_t ws_size,
                              hipStream_t stream) {
    const float* x  = (const float*)d_in[0];
    const int*   ei = (const int*)d_in[1];
    const float* W1 = (const float*)d_in[2];
    const float* b1 = (const float*)d_in[3];
    const float* W2 = (const float*)d_in[4];
    const float* b2 = (const float*)d_in[5];
    float* out = (float*)d_out;

    // workspace layout (512B-aligned slabs)
    char* ws = (char*)d_ws;
    size_t off = 0;
    auto alloc = [&](size_t bytes) -> char* {
        char* p = ws + off;
        off = (off + bytes + 511) & ~(size_t)511;
        return p;
    };
    int*   deg_cnt   = (int*)alloc(N_NODES * 4);
    float* dis       = (float*)alloc(N_NODES * 4);
    int*   excl      = (int*)alloc(N_NODES * 4);
    int*   sums      = (int*)alloc(64 * 4);
    int*   row_start = (int*)alloc((N_NODES + 1) * 4);
    int*   cursor    = (int*)alloc(N_NODES * 4);
    int*   csr_src   = (int*)alloc((size_t)N_EDGES * 4);
    float* g1        = (float*)alloc((size_t)N_NODES * HIDDEN * 4);
    float* rbuf      = (float*)alloc((size_t)N_NODES * HIDDEN * 4);
    float* g2        = (float*)alloc((size_t)N_NODES * N_CLASSES * 4);
    (void)ws_size; (void)in_sizes; (void)n_in; (void)out_size;

    const int* src = ei;
    const int* dst = ei + N_EDGES;

    zero_deg<<<196, 256, 0, stream>>>(deg_cnt);
    count_deg<<<N_EDGES / 256, 256, 0, stream>>>(dst, deg_cnt);
    compute_dis<<<196, 256, 0, stream>>>(deg_cnt, dis);
    scan_chunk<<<NCHUNK, 256, 0, stream>>>(deg_cnt, excl, sums);
    scan_sums<<<1, 64, 0, stream>>>(sums);
    finalize_rs<<<196, 256, 0, stream>>>(excl, sums, row_start, cursor);
    fill_csr<<<N_EDGES / 256, 256, 0, stream>>>(src, dst, cursor, csr_src);

    gemm1_scale<<<(N_NODES + BM - 1) / BM, 256, 0, stream>>>(x, W1, dis, g1);
    agg1_relu<<<N_NODES / 4, 256, 0, stream>>>(g1, row_start, csr_src, dis, b1, rbuf);
    gemm2_scale<<<N_NODES / 16, 256, 0, stream>>>(rbuf, W2, dis, g2);
    agg2_softmax<<<N_NODES / 16, 256, 0, stream>>>(g2, row_start, csr_src, dis, b2, out);
}

// Round 3
// 480.736 us; speedup vs baseline: 1.1500x; 1.1500x over previous
//
#include <hip/hip_runtime.h>
#include <hip/hip_bf16.h>
#include <math.h>

#define N_NODES 50000
#define N_EDGES 1600000
#define IN_FEAT 256
#define HIDDEN 128
#define N_CLASSES 16
#define NCHUNK 49          // ceil(50000/1024)

// ---------------------------------------------------------------------------
// Graph preprocessing: build CSR by destination each call (ws is re-poisoned)
// ---------------------------------------------------------------------------

// 4 edges per thread; scalar tail for the final partial chunk.
// grid = ceil(N_EDGES/1024) — round-2 bug was truncating division here.
__global__ void count_deg(const int* __restrict__ dst, int* __restrict__ deg_cnt) {
    int i = (blockIdx.x * blockDim.x + threadIdx.x) * 4;
    if (i + 4 <= N_EDGES) {
        int4 d = *(const int4*)&dst[i];
        atomicAdd(&deg_cnt[d.x], 1);
        atomicAdd(&deg_cnt[d.y], 1);
        atomicAdd(&deg_cnt[d.z], 1);
        atomicAdd(&deg_cnt[d.w], 1);
    } else {
        for (; i < N_EDGES; ++i) atomicAdd(&deg_cnt[dst[i]], 1);
    }
}

// chunk=1024 elements per block (256 thr x 4); also computes dis = rsqrt(deg+1)
__global__ __launch_bounds__(256) void scan_chunk(const int* __restrict__ cnt,
                                                  int* __restrict__ excl,
                                                  int* __restrict__ sums,
                                                  float* __restrict__ dis) {
    __shared__ int lds[256];
    int t = threadIdx.x;
    int base = blockIdx.x * 1024 + t * 4;
    int v[4];
#pragma unroll
    for (int j = 0; j < 4; ++j) {
        int i = base + j;
        v[j] = (i < N_NODES) ? cnt[i] : 0;
        if (i < N_NODES) dis[i] = 1.0f / sqrtf((float)(v[j] + 1)); // +1 self loop
    }
    int tsum = v[0] + v[1] + v[2] + v[3];
    lds[t] = tsum;
    __syncthreads();
    for (int off = 1; off < 256; off <<= 1) {
        int x = (t >= off) ? lds[t - off] : 0;
        __syncthreads();
        lds[t] += x;
        __syncthreads();
    }
    if (t == 255) sums[blockIdx.x] = lds[255];
    int run = lds[t] - tsum; // exclusive prefix of this thread's 4 elements
#pragma unroll
    for (int j = 0; j < 4; ++j) {
        int i = base + j;
        if (i < N_NODES) excl[i] = run;
        run += v[j];
    }
}

__global__ void scan_sums(int* __restrict__ sums) {
    int t = threadIdx.x; // 64 threads, one wave
    int v = (t < NCHUNK) ? sums[t] : 0;
    int orig = v;
    for (int off = 1; off < 64; off <<= 1) {
        int x = __shfl_up(v, off);
        if (t >= off) v += x;
    }
    if (t < NCHUNK) sums[t] = v - orig; // exclusive chunk base
}

__global__ void finalize_rs(const int* __restrict__ excl, const int* __restrict__ sums,
                            int* __restrict__ row_start, int* __restrict__ cursor) {
    int i = blockIdx.x * blockDim.x + threadIdx.x;
    if (i < N_NODES) {
        int rs = excl[i] + sums[i >> 10];
        row_start[i] = rs;
        cursor[i] = rs;
    } else if (i == N_NODES) {
        row_start[N_NODES] = N_EDGES;
    }
}

__global__ void fill_csr(const int* __restrict__ src, const int* __restrict__ dst,
                         int* __restrict__ cursor, unsigned short* __restrict__ csr_src) {
    int i = blockIdx.x * blockDim.x + threadIdx.x;
    if (i < N_EDGES) {
        int pos = atomicAdd(&cursor[dst[i]], 1);
        csr_src[pos] = (unsigned short)src[i];
    }
}

// ---------------------------------------------------------------------------
// GEMM1: g1[i][:] = dis[i] * (x[i][:] @ W1)      [50000x256 @ 256x128]
// fp32 LDS-tiled. Block: 256 thr, tile 64 rows x 128 cols, BK=16.
// ---------------------------------------------------------------------------
#define BM 64
#define BN 128
#define BK 16

__global__ __launch_bounds__(256) void gemm1_scale(const float* __restrict__ x,
                                                   const float* __restrict__ W1,
                                                   const float* __restrict__ dis,
                                                   float* __restrict__ g1) {
    __shared__ float As[BK][68];  // A tile transposed [k][row], padded for write conflicts
    __shared__ float Bs[BK][BN];
    int tid = threadIdx.x;
    int block_row = blockIdx.x * BM;
    int c4 = (tid & 31) * 4;  // col base (4 cols)
    int r8 = (tid >> 5) * 8;  // row base (8 rows)
    float acc[8][4] = {};

    int a_row = tid >> 2;       // 0..63
    int a_k = (tid & 3) * 4;    // 0,4,8,12
    int b_k = tid >> 5;         // 0..7 (and +8)
    int b_c = (tid & 31) * 4;

    for (int k0 = 0; k0 < IN_FEAT; k0 += BK) {
        int grow = block_row + a_row;
        float4 av = make_float4(0.f, 0.f, 0.f, 0.f);
        if (grow < N_NODES) av = *(const float4*)&x[(size_t)grow * IN_FEAT + k0 + a_k];
        float4 bv0 = *(const float4*)&W1[(size_t)(k0 + b_k) * HIDDEN + b_c];
        float4 bv1 = *(const float4*)&W1[(size_t)(k0 + b_k + 8) * HIDDEN + b_c];
        __syncthreads();
        As[a_k + 0][a_row] = av.x;
        As[a_k + 1][a_row] = av.y;
        As[a_k + 2][a_row] = av.z;
        As[a_k + 3][a_row] = av.w;
        *(float4*)&Bs[b_k][b_c] = bv0;
        *(float4*)&Bs[b_k + 8][b_c] = bv1;
        __syncthreads();
#pragma unroll
        for (int kk = 0; kk < BK; ++kk) {
            float4 b = *(float4*)&Bs[kk][c4];
            float4 a0 = *(float4*)&As[kk][r8];
            float4 a1 = *(float4*)&As[kk][r8 + 4];
            float a[8] = {a0.x, a0.y, a0.z, a0.w, a1.x, a1.y, a1.z, a1.w};
            float bb[4] = {b.x, b.y, b.z, b.w};
#pragma unroll
            for (int j = 0; j < 8; ++j)
#pragma unroll
                for (int i = 0; i < 4; ++i) acc[j][i] += a[j] * bb[i];
        }
    }
#pragma unroll
    for (int j = 0; j < 8; ++j) {
        int row = block_row + r8 + j;
        if (row < N_NODES) {
            float dv = dis[row];
            float4 o = make_float4(acc[j][0] * dv, acc[j][1] * dv, acc[j][2] * dv, acc[j][3] * dv);
            *(float4*)&g1[(size_t)row * HIDDEN + c4] = o;
        }
    }
}

// ---------------------------------------------------------------------------
// Aggregation 1 + bias + ReLU. One wave per node, float2 per lane (128 feats).
// 4-wide unrolled edge loop: 4 independent 512B gathers in flight per wave.
// r[dst][:] = relu( dis[dst]*(g1[dst] + sum_{src} g1[src]) + b1 )
// ---------------------------------------------------------------------------
__global__ __launch_bounds__(256) void agg1_relu(const float* __restrict__ g1,
                                                 const int* __restrict__ row_start,
                                                 const unsigned short* __restrict__ csr_src,
                                                 const float* __restrict__ dis,
                                                 const float* __restrict__ b1,
                                                 float* __restrict__ r) {
    int wave = threadIdx.x >> 6;
    int lane = threadIdx.x & 63;
    int node = blockIdx.x * 4 + wave;  // 12500*4 == 50000 exactly
    const float2* g = (const float2*)g1;
    float2 acc0 = g[(size_t)node * 64 + lane];  // self loop term
    float2 acc1 = make_float2(0.f, 0.f);
    float2 acc2 = make_float2(0.f, 0.f);
    float2 acc3 = make_float2(0.f, 0.f);
    int e0 = row_start[node], e1 = row_start[node + 1];
    int e = e0;
    for (; e + 4 <= e1; e += 4) {
        int s0 = csr_src[e + 0];
        int s1 = csr_src[e + 1];
        int s2 = csr_src[e + 2];
        int s3 = csr_src[e + 3];
        float2 v0 = g[(size_t)s0 * 64 + lane];
        float2 v1 = g[(size_t)s1 * 64 + lane];
        float2 v2 = g[(size_t)s2 * 64 + lane];
        float2 v3 = g[(size_t)s3 * 64 + lane];
        acc0.x += v0.x; acc0.y += v0.y;
        acc1.x += v1.x; acc1.y += v1.y;
        acc2.x += v2.x; acc2.y += v2.y;
        acc3.x += v3.x; acc3.y += v3.y;
    }
    for (; e < e1; ++e) {
        int s = csr_src[e];
        float2 v = g[(size_t)s * 64 + lane];
        acc0.x += v.x; acc0.y += v.y;
    }
    acc0.x += (acc1.x + acc2.x) + acc3.x;
    acc0.y += (acc1.y + acc2.y) + acc3.y;
    float dv = dis[node];
    int f = lane * 2;
    float2 bb = *(const float2*)&b1[f];
    float ox = fmaxf(fmaf(dv, acc0.x, bb.x), 0.f);
    float oy = fmaxf(fmaf(dv, acc0.y, bb.y), 0.f);
    *(float2*)&r[(size_t)node * HIDDEN + f] = make_float2(ox, oy);
}

// ---------------------------------------------------------------------------
// GEMM2: g2[i][:] = dis[i] * (r[i][:] @ W2)      [50000x128 @ 128x16]
// 16 lanes per node, W2 staged in LDS.
// ---------------------------------------------------------------------------
__global__ __launch_bounds__(256) void gemm2_scale(const float* __restrict__ r,
                                                   const float* __restrict__ W2,
                                                   const float* __restrict__ dis,
                                                   float* __restrict__ g2) {
    __shared__ float w2s[HIDDEN * N_CLASSES];
    int tid = threadIdx.x;
    for (int i = tid; i < HIDDEN * N_CLASSES; i += 256) w2s[i] = W2[i];
    __syncthreads();
    int node = blockIdx.x * 16 + (tid >> 4);  // 3125*16 == 50000 exactly
    int c = tid & 15;
    const float* rr = &r[(size_t)node * HIDDEN];
    float acc = 0.f;
#pragma unroll
    for (int k4 = 0; k4 < HIDDEN / 4; ++k4) {
        float4 rv = *(const float4*)&rr[k4 * 4];
        acc = fmaf(rv.x, w2s[(k4 * 4 + 0) * 16 + c], acc);
        acc = fmaf(rv.y, w2s[(k4 * 4 + 1) * 16 + c], acc);
        acc = fmaf(rv.z, w2s[(k4 * 4 + 2) * 16 + c], acc);
        acc = fmaf(rv.w, w2s[(k4 * 4 + 3) * 16 + c], acc);
    }
    g2[(size_t)node * N_CLASSES + c] = dis[node] * acc;
}

// ---------------------------------------------------------------------------
// Aggregation 2 + bias + logits + softmax. 16 lanes per node, 4-wide unroll.
// ---------------------------------------------------------------------------
__global__ __launch_bounds__(256) void agg2_softmax(const float* __restrict__ g2,
                                                    const int* __restrict__ row_start,
                                                    const unsigned short* __restrict__ csr_src,
                                                    const float* __restrict__ dis,
                                                    const float* __restrict__ b2,
                                                    float* __restrict__ out) {
    int tid = threadIdx.x;
    int node = blockIdx.x * 16 + (tid >> 4);
    int c = tid & 15;
    float acc0 = g2[(size_t)node * N_CLASSES + c];
    float acc1 = 0.f, acc2 = 0.f, acc3 = 0.f;
    int e0 = row_start[node], e1 = row_start[node + 1];
    int e = e0;
    for (; e + 4 <= e1; e += 4) {
        int s0 = csr_src[e + 0];
        int s1 = csr_src[e + 1];
        int s2 = csr_src[e + 2];
        int s3 = csr_src[e + 3];
        acc0 += g2[(size_t)s0 * N_CLASSES + c];
        acc1 += g2[(size_t)s1 * N_CLASSES + c];
        acc2 += g2[(size_t)s2 * N_CLASSES + c];
        acc3 += g2[(size_t)s3 * N_CLASSES + c];
    }
    for (; e < e1; ++e) {
        int s = csr_src[e];
        acc0 += g2[(size_t)s * N_CLASSES + c];
    }
    acc0 += (acc1 + acc2) + acc3;
    float logit = fmaf(dis[node], acc0, b2[c]);
    out[(size_t)node * N_CLASSES + c] = logit;
    // softmax across the 16-lane group (xor masks 1..8 stay inside the group)
    float m = logit;
    for (int off = 8; off; off >>= 1) m = fmaxf(m, __shfl_xor(m, off));
    float ex = expf(logit - m);
    float s = ex;
    for (int off = 8; off; off >>= 1) s += __shfl_xor(s, off);
    out[(size_t)N_NODES * N_CLASSES + (size_t)node * N_CLASSES + c] = ex / s;
}

// ---------------------------------------------------------------------------

extern "C" void kernel_launch(void* const* d_in, const int* in_sizes, int n_in,
                              void* d_out, int out_size, void* d_ws, size_t ws_size,
                              hipStream_t stream) {
    const float* x  = (const float*)d_in[0];
    const int*   ei = (const int*)d_in[1];
    const float* W1 = (const float*)d_in[2];
    const float* b1 = (const float*)d_in[3];
    const float* W2 = (const float*)d_in[4];
    const float* b2 = (const float*)d_in[5];
    float* out = (float*)d_out;

    // workspace layout (512B-aligned slabs)
    char* ws = (char*)d_ws;
    size_t off = 0;
    auto alloc = [&](size_t bytes) -> char* {
        char* p = ws + off;
        off = (off + bytes + 511) & ~(size_t)511;
        return p;
    };
    int*   deg_cnt   = (int*)alloc(N_NODES * 4);
    float* dis       = (float*)alloc(N_NODES * 4);
    int*   excl      = (int*)alloc(N_NODES * 4);
    int*   sums      = (int*)alloc(64 * 4);
    int*   row_start = (int*)alloc((N_NODES + 1) * 4);
    int*   cursor    = (int*)alloc(N_NODES * 4);
    unsigned short* csr_src = (unsigned short*)alloc((size_t)N_EDGES * 2);
    float* g1        = (float*)alloc((size_t)N_NODES * HIDDEN * 4);
    float* rbuf      = (float*)alloc((size_t)N_NODES * HIDDEN * 4);
    float* g2        = (float*)alloc((size_t)N_NODES * N_CLASSES * 4);
    (void)ws_size; (void)in_sizes; (void)n_in; (void)out_size;

    const int* src = ei;
    const int* dst = ei + N_EDGES;

    hipMemsetAsync(deg_cnt, 0, N_NODES * sizeof(int), stream);
    count_deg<<<(N_EDGES + 1023) / 1024, 256, 0, stream>>>(dst, deg_cnt);
    scan_chunk<<<NCHUNK, 256, 0, stream>>>(deg_cnt, excl, sums, dis);
    scan_sums<<<1, 64, 0, stream>>>(sums);
    finalize_rs<<<196, 256, 0, stream>>>(excl, sums, row_start, cursor);
    fill_csr<<<N_EDGES / 256, 256, 0, stream>>>(src, dst, cursor, csr_src);

    gemm1_scale<<<(N_NODES + BM - 1) / BM, 256, 0, stream>>>(x, W1, dis, g1);
    agg1_relu<<<N_NODES / 4, 256, 0, stream>>>(g1, row_start, csr_src, dis, b1, rbuf);
    gemm2_scale<<<N_NODES / 16, 256, 0, stream>>>(rbuf, W2, dis, g2);
    agg2_softmax<<<N_NODES / 16, 256, 0, stream>>>(g2, row_start, csr_src, dis, b2, out);
}

// Round 4
// 332.867 us; speedup vs baseline: 1.6609x; 1.4442x over previous
//
#include <hip/hip_runtime.h>
#include <hip/hip_bf16.h>
#include <math.h>

#define N_NODES 50000
#define N_EDGES 1600000
#define IN_FEAT 256
#define HIDDEN 128
#define N_CLASSES 16

#define ECHUNK 8192
#define NCHK 196   // ceil(1600000/8192)
#define NBKT 196   // ceil(50000/256) buckets of 256 nodes

// ---------------------------------------------------------------------------
// Bucket-radix CSR build. bucket = dst >> 8 (256 nodes per bucket).
// Replaces global-atomic count_deg + scan chain + random-scatter fill_csr.
// ---------------------------------------------------------------------------

// Phase A: per-chunk histogram over buckets (LDS atomics only).
__global__ __launch_bounds__(256) void edge_hist(const int* __restrict__ dst,
                                                 int* __restrict__ hist) {
    __shared__ int h[256];
    int t = threadIdx.x;
    h[t] = 0;
    __syncthreads();
    int base = blockIdx.x * ECHUNK;
    int end = min(base + ECHUNK, N_EDGES);
    for (int i = base + t; i < end; i += 256)
        atomicAdd(&h[dst[i] >> 8], 1);
    __syncthreads();
    hist[blockIdx.x * 256 + t] = h[t];
}

// Phase B: one block. Thread b owns bucket b: column-sum -> bucket totals,
// LDS scan -> bucket bases, rewrite hist[c][b] as the global offset for
// (chunk c, bucket b).
__global__ __launch_bounds__(256) void scan_hist(int* __restrict__ hist,
                                                 int* __restrict__ bucket_base) {
    __shared__ int tot[256];
    int b = threadIdx.x;
    int sum = 0;
    for (int c = 0; c < NCHK; ++c) sum += hist[c * 256 + b];
    int v = sum;
    tot[b] = sum;
    __syncthreads();
    for (int off = 1; off < 256; off <<= 1) {
        int x = (b >= off) ? tot[b - off] : 0;
        __syncthreads();
        tot[b] += x;
        __syncthreads();
    }
    int excl = tot[b] - v;  // exclusive bucket base
    bucket_base[b] = excl;
    int run = excl;
    for (int c = 0; c < NCHK; ++c) {
        int h = hist[c * 256 + b];
        hist[c * 256 + b] = run;
        run += h;
    }
}

// Phase C: scatter edges into bucket-sorted order, packed (dst<<16)|src.
// Each (chunk,bucket) destination segment is contiguous and block-exclusive.
__global__ __launch_bounds__(256) void scatter_edges(const int* __restrict__ src,
                                                     const int* __restrict__ dst,
                                                     const int* __restrict__ hist,
                                                     unsigned int* __restrict__ sorted) {
    __shared__ int cur[256];
    int t = threadIdx.x;
    cur[t] = hist[blockIdx.x * 256 + t];
    __syncthreads();
    int base = blockIdx.x * ECHUNK;
    int end = min(base + ECHUNK, N_EDGES);
    for (int i = base + t; i < end; i += 256) {
        int d = dst[i];
        int s = src[i];
        int pos = atomicAdd(&cur[d >> 8], 1);
        sorted[pos] = ((unsigned)d << 16) | (unsigned)s;
    }
}

// Phase D: one block per bucket. LDS per-node counts -> row_start + dis,
// then local fill of csr_src (writes confined to a ~16KB hot window).
__global__ __launch_bounds__(256) void build_csr(const unsigned int* __restrict__ sorted,
                                                 const int* __restrict__ bucket_base,
                                                 int* __restrict__ row_start,
                                                 float* __restrict__ dis,
                                                 unsigned short* __restrict__ csr_src) {
    __shared__ int cnt[256];
    __shared__ int roff[256];
    int t = threadIdx.x;
    int bkt = blockIdx.x;
    int ebase = bucket_base[bkt];
    int eend = (bkt == NBKT - 1) ? N_EDGES : bucket_base[bkt + 1];
    cnt[t] = 0;
    __syncthreads();
    for (int i = ebase + t; i < eend; i += 256)
        atomicAdd(&cnt[(sorted[i] >> 16) & 255], 1);
    __syncthreads();
    int v = cnt[t];
    roff[t] = v;
    __syncthreads();
    for (int off = 1; off < 256; off <<= 1) {
        int x = (t >= off) ? roff[t - off] : 0;
        __syncthreads();
        roff[t] += x;
        __syncthreads();
    }
    int excl = roff[t] - v;
    int node = bkt * 256 + t;
    if (node < N_NODES) {
        row_start[node] = ebase + excl;
        dis[node] = 1.0f / sqrtf((float)(v + 1));  // +1 self loop
        if (node == N_NODES - 1) row_start[N_NODES] = N_EDGES;
    }
    __syncthreads();
    cnt[t] = ebase + excl;  // reuse as cursor
    __syncthreads();
    for (int i = ebase + t; i < eend; i += 256) {
        unsigned e = sorted[i];
        int pos = atomicAdd(&cnt[(e >> 16) & 255], 1);
        csr_src[pos] = (unsigned short)(e & 0xffffu);
    }
}

// ---------------------------------------------------------------------------
// GEMM1: g1[i][:] = dis[i] * (x[i][:] @ W1)      [50000x256 @ 256x128]
// fp32 LDS-tiled. Block: 256 thr, tile 64 rows x 128 cols, BK=16.
// ---------------------------------------------------------------------------
#define BM 64
#define BN 128
#define BK 16

__global__ __launch_bounds__(256) void gemm1_scale(const float* __restrict__ x,
                                                   const float* __restrict__ W1,
                                                   const float* __restrict__ dis,
                                                   float* __restrict__ g1) {
    __shared__ float As[BK][68];  // A tile transposed [k][row], padded for write conflicts
    __shared__ float Bs[BK][BN];
    int tid = threadIdx.x;
    int block_row = blockIdx.x * BM;
    int c4 = (tid & 31) * 4;  // col base (4 cols)
    int r8 = (tid >> 5) * 8;  // row base (8 rows)
    float acc[8][4] = {};

    int a_row = tid >> 2;       // 0..63
    int a_k = (tid & 3) * 4;    // 0,4,8,12
    int b_k = tid >> 5;         // 0..7 (and +8)
    int b_c = (tid & 31) * 4;

    for (int k0 = 0; k0 < IN_FEAT; k0 += BK) {
        int grow = block_row + a_row;
        float4 av = make_float4(0.f, 0.f, 0.f, 0.f);
        if (grow < N_NODES) av = *(const float4*)&x[(size_t)grow * IN_FEAT + k0 + a_k];
        float4 bv0 = *(const float4*)&W1[(size_t)(k0 + b_k) * HIDDEN + b_c];
        float4 bv1 = *(const float4*)&W1[(size_t)(k0 + b_k + 8) * HIDDEN + b_c];
        __syncthreads();
        As[a_k + 0][a_row] = av.x;
        As[a_k + 1][a_row] = av.y;
        As[a_k + 2][a_row] = av.z;
        As[a_k + 3][a_row] = av.w;
        *(float4*)&Bs[b_k][b_c] = bv0;
        *(float4*)&Bs[b_k + 8][b_c] = bv1;
        __syncthreads();
#pragma unroll
        for (int kk = 0; kk < BK; ++kk) {
            float4 b = *(float4*)&Bs[kk][c4];
            float4 a0 = *(float4*)&As[kk][r8];
            float4 a1 = *(float4*)&As[kk][r8 + 4];
            float a[8] = {a0.x, a0.y, a0.z, a0.w, a1.x, a1.y, a1.z, a1.w};
            float bb[4] = {b.x, b.y, b.z, b.w};
#pragma unroll
            for (int j = 0; j < 8; ++j)
#pragma unroll
                for (int i = 0; i < 4; ++i) acc[j][i] += a[j] * bb[i];
        }
    }
#pragma unroll
    for (int j = 0; j < 8; ++j) {
        int row = block_row + r8 + j;
        if (row < N_NODES) {
            float dv = dis[row];
            float4 o = make_float4(acc[j][0] * dv, acc[j][1] * dv, acc[j][2] * dv, acc[j][3] * dv);
            *(float4*)&g1[(size_t)row * HIDDEN + c4] = o;
        }
    }
}

// ---------------------------------------------------------------------------
// Aggregation 1 + bias + ReLU. One wave per node, float2 per lane (128 feats).
// 4-wide unrolled edge loop: 4 independent 512B gathers in flight per wave.
// r[dst][:] = relu( dis[dst]*(g1[dst] + sum_{src} g1[src]) + b1 )
// ---------------------------------------------------------------------------
__global__ __launch_bounds__(256) void agg1_relu(const float* __restrict__ g1,
                                                 const int* __restrict__ row_start,
                                                 const unsigned short* __restrict__ csr_src,
                                                 const float* __restrict__ dis,
                                                 const float* __restrict__ b1,
                                                 float* __restrict__ r) {
    int wave = threadIdx.x >> 6;
    int lane = threadIdx.x & 63;
    int node = blockIdx.x * 4 + wave;  // 12500*4 == 50000 exactly
    const float2* g = (const float2*)g1;
    float2 acc0 = g[(size_t)node * 64 + lane];  // self loop term
    float2 acc1 = make_float2(0.f, 0.f);
    float2 acc2 = make_float2(0.f, 0.f);
    float2 acc3 = make_float2(0.f, 0.f);
    int e0 = row_start[node], e1 = row_start[node + 1];
    int e = e0;
    for (; e + 4 <= e1; e += 4) {
        int s0 = csr_src[e + 0];
        int s1 = csr_src[e + 1];
        int s2 = csr_src[e + 2];
        int s3 = csr_src[e + 3];
        float2 v0 = g[(size_t)s0 * 64 + lane];
        float2 v1 = g[(size_t)s1 * 64 + lane];
        float2 v2 = g[(size_t)s2 * 64 + lane];
        float2 v3 = g[(size_t)s3 * 64 + lane];
        acc0.x += v0.x; acc0.y += v0.y;
        acc1.x += v1.x; acc1.y += v1.y;
        acc2.x += v2.x; acc2.y += v2.y;
        acc3.x += v3.x; acc3.y += v3.y;
    }
    for (; e < e1; ++e) {
        int s = csr_src[e];
        float2 v = g[(size_t)s * 64 + lane];
        acc0.x += v.x; acc0.y += v.y;
    }
    acc0.x += (acc1.x + acc2.x) + acc3.x;
    acc0.y += (acc1.y + acc2.y) + acc3.y;
    float dv = dis[node];
    int f = lane * 2;
    float2 bb = *(const float2*)&b1[f];
    float ox = fmaxf(fmaf(dv, acc0.x, bb.x), 0.f);
    float oy = fmaxf(fmaf(dv, acc0.y, bb.y), 0.f);
    *(float2*)&r[(size_t)node * HIDDEN + f] = make_float2(ox, oy);
}

// ---------------------------------------------------------------------------
// GEMM2: g2[i][:] = dis[i] * (r[i][:] @ W2)      [50000x128 @ 128x16]
// 16 lanes per node, W2 staged in LDS.
// ---------------------------------------------------------------------------
__global__ __launch_bounds__(256) void gemm2_scale(const float* __restrict__ r,
                                                   const float* __restrict__ W2,
                                                   const float* __restrict__ dis,
                                                   float* __restrict__ g2) {
    __shared__ float w2s[HIDDEN * N_CLASSES];
    int tid = threadIdx.x;
    for (int i = tid; i < HIDDEN * N_CLASSES; i += 256) w2s[i] = W2[i];
    __syncthreads();
    int node = blockIdx.x * 16 + (tid >> 4);  // 3125*16 == 50000 exactly
    int c = tid & 15;
    const float* rr = &r[(size_t)node * HIDDEN];
    float acc = 0.f;
#pragma unroll
    for (int k4 = 0; k4 < HIDDEN / 4; ++k4) {
        float4 rv = *(const float4*)&rr[k4 * 4];
        acc = fmaf(rv.x, w2s[(k4 * 4 + 0) * 16 + c], acc);
        acc = fmaf(rv.y, w2s[(k4 * 4 + 1) * 16 + c], acc);
        acc = fmaf(rv.z, w2s[(k4 * 4 + 2) * 16 + c], acc);
        acc = fmaf(rv.w, w2s[(k4 * 4 + 3) * 16 + c], acc);
    }
    g2[(size_t)node * N_CLASSES + c] = dis[node] * acc;
}

// ---------------------------------------------------------------------------
// Aggregation 2 + bias + logits + softmax. 16 lanes per node, 4-wide unroll.
// ---------------------------------------------------------------------------
__global__ __launch_bounds__(256) void agg2_softmax(const float* __restrict__ g2,
                                                    const int* __restrict__ row_start,
                                                    const unsigned short* __restrict__ csr_src,
                                                    const float* __restrict__ dis,
                                                    const float* __restrict__ b2,
                                                    float* __restrict__ out) {
    int tid = threadIdx.x;
    int node = blockIdx.x * 16 + (tid >> 4);
    int c = tid & 15;
    float acc0 = g2[(size_t)node * N_CLASSES + c];
    float acc1 = 0.f, acc2 = 0.f, acc3 = 0.f;
    int e0 = row_start[node], e1 = row_start[node + 1];
    int e = e0;
    for (; e + 4 <= e1; e += 4) {
        int s0 = csr_src[e + 0];
        int s1 = csr_src[e + 1];
        int s2 = csr_src[e + 2];
        int s3 = csr_src[e + 3];
        acc0 += g2[(size_t)s0 * N_CLASSES + c];
        acc1 += g2[(size_t)s1 * N_CLASSES + c];
        acc2 += g2[(size_t)s2 * N_CLASSES + c];
        acc3 += g2[(size_t)s3 * N_CLASSES + c];
    }
    for (; e < e1; ++e) {
        int s = csr_src[e];
        acc0 += g2[(size_t)s * N_CLASSES + c];
    }
    acc0 += (acc1 + acc2) + acc3;
    float logit = fmaf(dis[node], acc0, b2[c]);
    out[(size_t)node * N_CLASSES + c] = logit;
    // softmax across the 16-lane group (xor masks 1..8 stay inside the group)
    float m = logit;
    for (int off = 8; off; off >>= 1) m = fmaxf(m, __shfl_xor(m, off));
    float ex = expf(logit - m);
    float s = ex;
    for (int off = 8; off; off >>= 1) s += __shfl_xor(s, off);
    out[(size_t)N_NODES * N_CLASSES + (size_t)node * N_CLASSES + c] = ex / s;
}

// ---------------------------------------------------------------------------

extern "C" void kernel_launch(void* const* d_in, const int* in_sizes, int n_in,
                              void* d_out, int out_size, void* d_ws, size_t ws_size,
                              hipStream_t stream) {
    const float* x  = (const float*)d_in[0];
    const int*   ei = (const int*)d_in[1];
    const float* W1 = (const float*)d_in[2];
    const float* b1 = (const float*)d_in[3];
    const float* W2 = (const float*)d_in[4];
    const float* b2 = (const float*)d_in[5];
    float* out = (float*)d_out;

    // workspace layout (512B-aligned slabs)
    char* ws = (char*)d_ws;
    size_t off = 0;
    auto alloc = [&](size_t bytes) -> char* {
        char* p = ws + off;
        off = (off + bytes + 511) & ~(size_t)511;
        return p;
    };
    int*   hist        = (int*)alloc((size_t)NCHK * 256 * 4);
    int*   bucket_base = (int*)alloc(256 * 4);
    float* dis         = (float*)alloc(N_NODES * 4);
    int*   row_start   = (int*)alloc((N_NODES + 1) * 4);
    unsigned short* csr_src = (unsigned short*)alloc((size_t)N_EDGES * 2);
    float* g1          = (float*)alloc((size_t)N_NODES * HIDDEN * 4);
    float* rbuf        = (float*)alloc((size_t)N_NODES * HIDDEN * 4);
    float* g2          = (float*)alloc((size_t)N_NODES * N_CLASSES * 4);
    // sorted edge array (6.4MB) aliases g1's slab: dead before gemm1 writes g1.
    unsigned int* sorted = (unsigned int*)g1;
    (void)ws_size; (void)in_sizes; (void)n_in; (void)out_size;

    const int* src = ei;
    const int* dst = ei + N_EDGES;

    edge_hist<<<NCHK, 256, 0, stream>>>(dst, hist);
    scan_hist<<<1, 256, 0, stream>>>(hist, bucket_base);
    scatter_edges<<<NCHK, 256, 0, stream>>>(src, dst, hist, sorted);
    build_csr<<<NBKT, 256, 0, stream>>>(sorted, bucket_base, row_start, dis, csr_src);

    gemm1_scale<<<(N_NODES + BM - 1) / BM, 256, 0, stream>>>(x, W1, dis, g1);
    agg1_relu<<<N_NODES / 4, 256, 0, stream>>>(g1, row_start, csr_src, dis, b1, rbuf);
    gemm2_scale<<<N_NODES / 16, 256, 0, stream>>>(rbuf, W2, dis, g2);
    agg2_softmax<<<N_NODES / 16, 256, 0, stream>>>(g2, row_start, csr_src, dis, b2, out);
}

// Round 5
// 279.961 us; speedup vs baseline: 1.9747x; 1.1890x over previous
//
#include <hip/hip_runtime.h>
#include <hip/hip_bf16.h>
#include <math.h>

#define N_NODES 50000
#define N_EDGES 1600000
#define IN_FEAT 256
#define HIDDEN 128
#define N_CLASSES 16

#define ECHUNK 8192
#define NCHK 196   // ceil(1600000/8192)
#define NBKT 196   // ceil(50000/256) buckets of 256 nodes

// bf16 round-to-nearest-even
__device__ __forceinline__ unsigned short f2bf(float f) {
    unsigned u = __float_as_uint(f);
    return (unsigned short)((u + 0x7fffu + ((u >> 16) & 1u)) >> 16);
}

// ---------------------------------------------------------------------------
// Bucket-radix CSR build. bucket = dst >> 8 (256 nodes per bucket).
// ---------------------------------------------------------------------------

__global__ __launch_bounds__(256) void edge_hist(const int* __restrict__ dst,
                                                 int* __restrict__ hist) {
    __shared__ int h[256];
    int t = threadIdx.x;
    h[t] = 0;
    __syncthreads();
    int base = blockIdx.x * ECHUNK;
    int end = min(base + ECHUNK, N_EDGES);
    for (int i = base + t; i < end; i += 256)
        atomicAdd(&h[dst[i] >> 8], 1);
    __syncthreads();
    hist[blockIdx.x * 256 + t] = h[t];
}

__global__ __launch_bounds__(256) void scan_hist(int* __restrict__ hist,
                                                 int* __restrict__ bucket_base) {
    __shared__ int tot[256];
    int b = threadIdx.x;
    int sum = 0;
    for (int c = 0; c < NCHK; ++c) sum += hist[c * 256 + b];
    int v = sum;
    tot[b] = sum;
    __syncthreads();
    for (int off = 1; off < 256; off <<= 1) {
        int x = (b >= off) ? tot[b - off] : 0;
        __syncthreads();
        tot[b] += x;
        __syncthreads();
    }
    int excl = tot[b] - v;  // exclusive bucket base
    bucket_base[b] = excl;
    int run = excl;
    for (int c = 0; c < NCHK; ++c) {
        int h = hist[c * 256 + b];
        hist[c * 256 + b] = run;
        run += h;
    }
}

__global__ __launch_bounds__(256) void scatter_edges(const int* __restrict__ src,
                                                     const int* __restrict__ dst,
                                                     const int* __restrict__ hist,
                                                     unsigned int* __restrict__ sorted) {
    __shared__ int cur[256];
    int t = threadIdx.x;
    cur[t] = hist[blockIdx.x * 256 + t];
    __syncthreads();
    int base = blockIdx.x * ECHUNK;
    int end = min(base + ECHUNK, N_EDGES);
    for (int i = base + t; i < end; i += 256) {
        int d = dst[i];
        int s = src[i];
        int pos = atomicAdd(&cur[d >> 8], 1);
        sorted[pos] = ((unsigned)d << 16) | (unsigned)s;
    }
}

__global__ __launch_bounds__(256) void build_csr(const unsigned int* __restrict__ sorted,
                                                 const int* __restrict__ bucket_base,
                                                 int* __restrict__ row_start,
                                                 float* __restrict__ dis,
                                                 unsigned short* __restrict__ csr_src) {
    __shared__ int cnt[256];
    __shared__ int roff[256];
    int t = threadIdx.x;
    int bkt = blockIdx.x;
    int ebase = bucket_base[bkt];
    int eend = (bkt == NBKT - 1) ? N_EDGES : bucket_base[bkt + 1];
    cnt[t] = 0;
    __syncthreads();
    for (int i = ebase + t; i < eend; i += 256)
        atomicAdd(&cnt[(sorted[i] >> 16) & 255], 1);
    __syncthreads();
    int v = cnt[t];
    roff[t] = v;
    __syncthreads();
    for (int off = 1; off < 256; off <<= 1) {
        int x = (t >= off) ? roff[t - off] : 0;
        __syncthreads();
        roff[t] += x;
        __syncthreads();
    }
    int excl = roff[t] - v;
    int node = bkt * 256 + t;
    if (node < N_NODES) {
        row_start[node] = ebase + excl;
        dis[node] = 1.0f / sqrtf((float)(v + 1));  // +1 self loop
        if (node == N_NODES - 1) row_start[N_NODES] = N_EDGES;
    }
    __syncthreads();
    cnt[t] = ebase + excl;  // reuse as cursor
    __syncthreads();
    for (int i = ebase + t; i < eend; i += 256) {
        unsigned e = sorted[i];
        int pos = atomicAdd(&cnt[(e >> 16) & 255], 1);
        csr_src[pos] = (unsigned short)(e & 0xffffu);
    }
}

// ---------------------------------------------------------------------------
// GEMM1: g1[i][:] = bf16( dis[i] * (x[i][:] @ W1) )   [50000x256 @ 256x128]
// fp32 LDS-tiled compute; bf16-packed output (halves agg1 gather traffic).
// ---------------------------------------------------------------------------
#define BM 64
#define BN 128
#define BK 16

__global__ __launch_bounds__(256) void gemm1_scale(const float* __restrict__ x,
                                                   const float* __restrict__ W1,
                                                   const float* __restrict__ dis,
                                                   unsigned int* __restrict__ g1) {
    __shared__ float As[BK][68];
    __shared__ float Bs[BK][BN];
    int tid = threadIdx.x;
    int block_row = blockIdx.x * BM;
    int c4 = (tid & 31) * 4;  // col base (4 cols)
    int r8 = (tid >> 5) * 8;  // row base (8 rows)
    float acc[8][4] = {};

    int a_row = tid >> 2;
    int a_k = (tid & 3) * 4;
    int b_k = tid >> 5;
    int b_c = (tid & 31) * 4;

    for (int k0 = 0; k0 < IN_FEAT; k0 += BK) {
        int grow = block_row + a_row;
        float4 av = make_float4(0.f, 0.f, 0.f, 0.f);
        if (grow < N_NODES) av = *(const float4*)&x[(size_t)grow * IN_FEAT + k0 + a_k];
        float4 bv0 = *(const float4*)&W1[(size_t)(k0 + b_k) * HIDDEN + b_c];
        float4 bv1 = *(const float4*)&W1[(size_t)(k0 + b_k + 8) * HIDDEN + b_c];
        __syncthreads();
        As[a_k + 0][a_row] = av.x;
        As[a_k + 1][a_row] = av.y;
        As[a_k + 2][a_row] = av.z;
        As[a_k + 3][a_row] = av.w;
        *(float4*)&Bs[b_k][b_c] = bv0;
        *(float4*)&Bs[b_k + 8][b_c] = bv1;
        __syncthreads();
#pragma unroll
        for (int kk = 0; kk < BK; ++kk) {
            float4 b = *(float4*)&Bs[kk][c4];
            float4 a0 = *(float4*)&As[kk][r8];
            float4 a1 = *(float4*)&As[kk][r8 + 4];
            float a[8] = {a0.x, a0.y, a0.z, a0.w, a1.x, a1.y, a1.z, a1.w};
            float bb[4] = {b.x, b.y, b.z, b.w};
#pragma unroll
            for (int j = 0; j < 8; ++j)
#pragma unroll
                for (int i = 0; i < 4; ++i) acc[j][i] += a[j] * bb[i];
        }
    }
#pragma unroll
    for (int j = 0; j < 8; ++j) {
        int row = block_row + r8 + j;
        if (row < N_NODES) {
            float dv = dis[row];
            unsigned u01 = (unsigned)f2bf(acc[j][0] * dv) | ((unsigned)f2bf(acc[j][1] * dv) << 16);
            unsigned u23 = (unsigned)f2bf(acc[j][2] * dv) | ((unsigned)f2bf(acc[j][3] * dv) << 16);
            uint2 o = make_uint2(u01, u23);
            *(uint2*)&g1[(size_t)row * 64 + (c4 >> 1)] = o;
        }
    }
}

// ---------------------------------------------------------------------------
// Fused: aggregation 1 + bias + ReLU + GEMM2 (+dis scale).
// One wave per node; g1 rows are bf16x2 per lane (256B/row), unroll 8.
// r (relu output) lives only in LDS per-wave; g2[node][c]=dis*(r@W2)[c].
// ---------------------------------------------------------------------------
__global__ __launch_bounds__(256) void agg1_gemm2(const unsigned int* __restrict__ g1,
                                                  const int* __restrict__ row_start,
                                                  const unsigned short* __restrict__ csr_src,
                                                  const float* __restrict__ dis,
                                                  const float* __restrict__ b1,
                                                  const float* __restrict__ W2,
                                                  float* __restrict__ g2) {
    __shared__ float w2s[HIDDEN * N_CLASSES];   // 8 KB
    __shared__ float rs[4][HIDDEN];             // 2 KB, per-wave regions
    int tid = threadIdx.x;
    for (int i = tid; i < HIDDEN * N_CLASSES; i += 256) w2s[i] = W2[i];
    __syncthreads();

    int wave = tid >> 6;
    int lane = tid & 63;
    int node = blockIdx.x * 4 + wave;  // 12500*4 == 50000

    unsigned su = g1[(size_t)node * 64 + lane];  // self loop term
    float a0x = __uint_as_float(su << 16), a0y = __uint_as_float(su & 0xffff0000u);
    float a1x = 0.f, a1y = 0.f, a2x = 0.f, a2y = 0.f, a3x = 0.f, a3y = 0.f;
    float a4x = 0.f, a4y = 0.f, a5x = 0.f, a5y = 0.f, a6x = 0.f, a6y = 0.f, a7x = 0.f, a7y = 0.f;

    int e0 = row_start[node], e1 = row_start[node + 1];
    int e = e0;
    for (; e + 8 <= e1; e += 8) {
        int s0 = csr_src[e + 0], s1 = csr_src[e + 1], s2 = csr_src[e + 2], s3 = csr_src[e + 3];
        int s4 = csr_src[e + 4], s5 = csr_src[e + 5], s6 = csr_src[e + 6], s7 = csr_src[e + 7];
        unsigned u0 = g1[(size_t)s0 * 64 + lane];
        unsigned u1 = g1[(size_t)s1 * 64 + lane];
        unsigned u2 = g1[(size_t)s2 * 64 + lane];
        unsigned u3 = g1[(size_t)s3 * 64 + lane];
        unsigned u4 = g1[(size_t)s4 * 64 + lane];
        unsigned u5 = g1[(size_t)s5 * 64 + lane];
        unsigned u6 = g1[(size_t)s6 * 64 + lane];
        unsigned u7 = g1[(size_t)s7 * 64 + lane];
        a0x += __uint_as_float(u0 << 16); a0y += __uint_as_float(u0 & 0xffff0000u);
        a1x += __uint_as_float(u1 << 16); a1y += __uint_as_float(u1 & 0xffff0000u);
        a2x += __uint_as_float(u2 << 16); a2y += __uint_as_float(u2 & 0xffff0000u);
        a3x += __uint_as_float(u3 << 16); a3y += __uint_as_float(u3 & 0xffff0000u);
        a4x += __uint_as_float(u4 << 16); a4y += __uint_as_float(u4 & 0xffff0000u);
        a5x += __uint_as_float(u5 << 16); a5y += __uint_as_float(u5 & 0xffff0000u);
        a6x += __uint_as_float(u6 << 16); a6y += __uint_as_float(u6 & 0xffff0000u);
        a7x += __uint_as_float(u7 << 16); a7y += __uint_as_float(u7 & 0xffff0000u);
    }
    for (; e < e1; ++e) {
        int s = csr_src[e];
        unsigned u = g1[(size_t)s * 64 + lane];
        a0x += __uint_as_float(u << 16); a0y += __uint_as_float(u & 0xffff0000u);
    }
    float sx = ((a0x + a1x) + (a2x + a3x)) + ((a4x + a5x) + (a6x + a7x));
    float sy = ((a0y + a1y) + (a2y + a3y)) + ((a4y + a5y) + (a6y + a7y));

    float dv = dis[node];
    float2 bb = ((const float2*)b1)[lane];
    float rx = fmaxf(fmaf(dv, sx, bb.x), 0.f);
    float ry = fmaxf(fmaf(dv, sy, bb.y), 0.f);

    // r -> LDS (per-wave region; same-wave LDS ops are ordered, no barrier)
    *(float2*)&rs[wave][lane * 2] = make_float2(rx, ry);

    // GEMM2: 4 lane-groups x 32 feats x 16 classes, then 2-step shuffle reduce
    int grp = lane >> 4;
    int c = lane & 15;
    int f0 = grp * 32;
    float p = 0.f;
#pragma unroll
    for (int k = 0; k < 32; ++k)
        p = fmaf(rs[wave][f0 + k], w2s[(f0 + k) * N_CLASSES + c], p);
    p += __shfl_xor(p, 16);
    p += __shfl_xor(p, 32);
    if (lane < 16) g2[(size_t)node * N_CLASSES + lane] = dv * p;
}

// ---------------------------------------------------------------------------
// Aggregation 2 + bias + logits + softmax. 16 lanes per node, unroll 8.
// ---------------------------------------------------------------------------
__global__ __launch_bounds__(256) void agg2_softmax(const float* __restrict__ g2,
                                                    const int* __restrict__ row_start,
                                                    const unsigned short* __restrict__ csr_src,
                                                    const float* __restrict__ dis,
                                                    const float* __restrict__ b2,
                                                    float* __restrict__ out) {
    int tid = threadIdx.x;
    int node = blockIdx.x * 16 + (tid >> 4);
    int c = tid & 15;
    float acc0 = g2[(size_t)node * N_CLASSES + c];
    float acc1 = 0.f, acc2 = 0.f, acc3 = 0.f;
    float acc4 = 0.f, acc5 = 0.f, acc6 = 0.f, acc7 = 0.f;
    int e0 = row_start[node], e1 = row_start[node + 1];
    int e = e0;
    for (; e + 8 <= e1; e += 8) {
        int s0 = csr_src[e + 0], s1 = csr_src[e + 1], s2 = csr_src[e + 2], s3 = csr_src[e + 3];
        int s4 = csr_src[e + 4], s5 = csr_src[e + 5], s6 = csr_src[e + 6], s7 = csr_src[e + 7];
        acc0 += g2[(size_t)s0 * N_CLASSES + c];
        acc1 += g2[(size_t)s1 * N_CLASSES + c];
        acc2 += g2[(size_t)s2 * N_CLASSES + c];
        acc3 += g2[(size_t)s3 * N_CLASSES + c];
        acc4 += g2[(size_t)s4 * N_CLASSES + c];
        acc5 += g2[(size_t)s5 * N_CLASSES + c];
        acc6 += g2[(size_t)s6 * N_CLASSES + c];
        acc7 += g2[(size_t)s7 * N_CLASSES + c];
    }
    for (; e < e1; ++e) {
        int s = csr_src[e];
        acc0 += g2[(size_t)s * N_CLASSES + c];
    }
    acc0 = ((acc0 + acc1) + (acc2 + acc3)) + ((acc4 + acc5) + (acc6 + acc7));
    float logit = fmaf(dis[node], acc0, b2[c]);
    out[(size_t)node * N_CLASSES + c] = logit;
    float m = logit;
    for (int off = 8; off; off >>= 1) m = fmaxf(m, __shfl_xor(m, off));
    float ex = expf(logit - m);
    float s = ex;
    for (int off = 8; off; off >>= 1) s += __shfl_xor(s, off);
    out[(size_t)N_NODES * N_CLASSES + (size_t)node * N_CLASSES + c] = ex / s;
}

// ---------------------------------------------------------------------------

extern "C" void kernel_launch(void* const* d_in, const int* in_sizes, int n_in,
                              void* d_out, int out_size, void* d_ws, size_t ws_size,
                              hipStream_t stream) {
    const float* x  = (const float*)d_in[0];
    const int*   ei = (const int*)d_in[1];
    const float* W1 = (const float*)d_in[2];
    const float* b1 = (const float*)d_in[3];
    const float* W2 = (const float*)d_in[4];
    const float* b2 = (const float*)d_in[5];
    float* out = (float*)d_out;

    char* ws = (char*)d_ws;
    size_t off = 0;
    auto alloc = [&](size_t bytes) -> char* {
        char* p = ws + off;
        off = (off + bytes + 511) & ~(size_t)511;
        return p;
    };
    int*   hist        = (int*)alloc((size_t)NCHK * 256 * 4);
    int*   bucket_base = (int*)alloc(256 * 4);
    float* dis         = (float*)alloc(N_NODES * 4);
    int*   row_start   = (int*)alloc((N_NODES + 1) * 4);
    unsigned short* csr_src = (unsigned short*)alloc((size_t)N_EDGES * 2);
    unsigned int* g1   = (unsigned int*)alloc((size_t)N_NODES * 64 * 4);  // bf16x2 per lane
    float* g2          = (float*)alloc((size_t)N_NODES * N_CLASSES * 4);
    // sorted edge array (6.4MB) aliases g1's slab: dead before gemm1 writes g1.
    unsigned int* sorted = (unsigned int*)g1;
    (void)ws_size; (void)in_sizes; (void)n_in; (void)out_size;

    const int* src = ei;
    const int* dst = ei + N_EDGES;

    edge_hist<<<NCHK, 256, 0, stream>>>(dst, hist);
    scan_hist<<<1, 256, 0, stream>>>(hist, bucket_base);
    scatter_edges<<<NCHK, 256, 0, stream>>>(src, dst, hist, sorted);
    build_csr<<<NBKT, 256, 0, stream>>>(sorted, bucket_base, row_start, dis, csr_src);

    gemm1_scale<<<(N_NODES + BM - 1) / BM, 256, 0, stream>>>(x, W1, dis, g1);
    agg1_gemm2<<<N_NODES / 4, 256, 0, stream>>>(g1, row_start, csr_src, dis, b1, W2, g2);
    agg2_softmax<<<N_NODES / 16, 256, 0, stream>>>(g2, row_start, csr_src, dis, b2, out);
}

// Round 6
// 259.618 us; speedup vs baseline: 2.1295x; 1.0784x over previous
//
#include <hip/hip_runtime.h>
#include <hip/hip_bf16.h>
#include <math.h>

#define N_NODES 50000
#define N_EDGES 1600000
#define IN_FEAT 256
#define HIDDEN 128
#define N_CLASSES 16

#define ECHUNK 8192
#define NCHK 196   // ceil(1600000/8192)
#define NBKT 196   // ceil(50000/256) buckets of 256 nodes

typedef __attribute__((ext_vector_type(8))) short short8;   // 8 bf16 (A/B frag)
typedef __attribute__((ext_vector_type(4))) float floatx4;  // C/D frag

// bf16 round-to-nearest-even (scalar, integer path — used in prep only)
__device__ __forceinline__ unsigned short f2bf(float f) {
    unsigned u = __float_as_uint(f);
    return (unsigned short)((u + 0x7fffu + ((u >> 16) & 1u)) >> 16);
}

// HW packed fp32->bf16x2 (v_cvt_pk path) — used in the MFMA hot loop
__device__ __forceinline__ unsigned pk2bf(float a, float b) {
    __hip_bfloat162 h = __float22bfloat162_rn(make_float2(a, b));
    union { __hip_bfloat162 h; unsigned u; } cv;
    cv.h = h;
    return cv.u;
}

// ---------------------------------------------------------------------------
// Bucket-radix CSR build. bucket = dst >> 8 (256 nodes per bucket).
// edge_hist blocks 0..127 additionally transpose W1 -> bf16 w1t[n][k].
// ---------------------------------------------------------------------------

__global__ __launch_bounds__(256) void edge_hist(const int* __restrict__ dst,
                                                 int* __restrict__ hist,
                                                 const float* __restrict__ W1,
                                                 unsigned short* __restrict__ w1t) {
    __shared__ int h[256];
    int t = threadIdx.x;
    h[t] = 0;
    // fused W1 transpose+cast: block b (<128) handles output row n=b (256 k's)
    if (blockIdx.x < HIDDEN)
        w1t[blockIdx.x * IN_FEAT + t] = f2bf(W1[t * HIDDEN + blockIdx.x]);
    __syncthreads();
    int base = blockIdx.x * ECHUNK;
    int end = min(base + ECHUNK, N_EDGES);
    for (int i = base + t; i < end; i += 256)
        atomicAdd(&h[dst[i] >> 8], 1);
    __syncthreads();
    hist[blockIdx.x * 256 + t] = h[t];
}

__global__ __launch_bounds__(256) void scan_hist(int* __restrict__ hist,
                                                 int* __restrict__ bucket_base) {
    __shared__ int tot[256];
    int b = threadIdx.x;
    int sum = 0;
    for (int c = 0; c < NCHK; ++c) sum += hist[c * 256 + b];
    int v = sum;
    tot[b] = sum;
    __syncthreads();
    for (int off = 1; off < 256; off <<= 1) {
        int x = (b >= off) ? tot[b - off] : 0;
        __syncthreads();
        tot[b] += x;
        __syncthreads();
    }
    int excl = tot[b] - v;  // exclusive bucket base
    bucket_base[b] = excl;
    int run = excl;
    for (int c = 0; c < NCHK; ++c) {
        int h = hist[c * 256 + b];
        hist[c * 256 + b] = run;
        run += h;
    }
}

__global__ __launch_bounds__(256) void scatter_edges(const int* __restrict__ src,
                                                     const int* __restrict__ dst,
                                                     const int* __restrict__ hist,
                                                     unsigned int* __restrict__ sorted) {
    __shared__ int cur[256];
    int t = threadIdx.x;
    cur[t] = hist[blockIdx.x * 256 + t];
    __syncthreads();
    int base = blockIdx.x * ECHUNK;
    int end = min(base + ECHUNK, N_EDGES);
    for (int i = base + t; i < end; i += 256) {
        int d = dst[i];
        int s = src[i];
        int pos = atomicAdd(&cur[d >> 8], 1);
        sorted[pos] = ((unsigned)d << 16) | (unsigned)s;
    }
}

__global__ __launch_bounds__(256) void build_csr(const unsigned int* __restrict__ sorted,
                                                 const int* __restrict__ bucket_base,
                                                 int* __restrict__ row_start,
                                                 float* __restrict__ dis,
                                                 unsigned short* __restrict__ csr_src) {
    __shared__ int cnt[256];
    __shared__ int roff[256];
    int t = threadIdx.x;
    int bkt = blockIdx.x;
    int ebase = bucket_base[bkt];
    int eend = (bkt == NBKT - 1) ? N_EDGES : bucket_base[bkt + 1];
    cnt[t] = 0;
    __syncthreads();
    for (int i = ebase + t; i < eend; i += 256)
        atomicAdd(&cnt[(sorted[i] >> 16) & 255], 1);
    __syncthreads();
    int v = cnt[t];
    roff[t] = v;
    __syncthreads();
    for (int off = 1; off < 256; off <<= 1) {
        int x = (t >= off) ? roff[t - off] : 0;
        __syncthreads();
        roff[t] += x;
        __syncthreads();
    }
    int excl = roff[t] - v;
    int node = bkt * 256 + t;
    if (node < N_NODES) {
        row_start[node] = ebase + excl;
        dis[node] = 1.0f / sqrtf((float)(v + 1));  // +1 self loop
        if (node == N_NODES - 1) row_start[N_NODES] = N_EDGES;
    }
    __syncthreads();
    cnt[t] = ebase + excl;  // reuse as cursor
    __syncthreads();
    for (int i = ebase + t; i < eend; i += 256) {
        unsigned e = sorted[i];
        int pos = atomicAdd(&cnt[(e >> 16) & 255], 1);
        csr_src[pos] = (unsigned short)(e & 0xffffu);
    }
}

// ---------------------------------------------------------------------------
// GEMM1 via MFMA: g1[i][:] = bf16( dis[i] * (x[i][:] @ W1) )
// Block: 64 rows x 128 cols, 4 waves in 2x2 grid; wave = 32 rows x 64 cols
// (2 row-tiles x 4 n-tiles of 16x16x32 bf16 MFMA). No LDS, no barriers:
// A frags read from x (fp32, cvt_pk to bf16 in-flight), B frags from w1t
// (bf16, k-contiguous — L2-resident 64KB).
// ---------------------------------------------------------------------------
__global__ __launch_bounds__(256) void gemm1_mfma(const float* __restrict__ x,
                                                  const unsigned short* __restrict__ w1t,
                                                  const float* __restrict__ dis,
                                                  unsigned int* __restrict__ g1) {
    int tid = threadIdx.x;
    int w = tid >> 6;
    int lane = tid & 63;
    int quad = lane >> 4;
    int c = lane & 15;
    int row_base = blockIdx.x * 64 + (w >> 1) * 32;  // + rt*16 + c = A row
    int col_base = (w & 1) * 64;                     // + nt*16 + c = B col

    floatx4 acc[2][4] = {};

    const float* xp[2];
#pragma unroll
    for (int rt = 0; rt < 2; ++rt) {
        int r = min(row_base + rt * 16 + c, N_NODES - 1);
        xp[rt] = x + (size_t)r * IN_FEAT + quad * 8;
    }
    const unsigned short* bp[4];
#pragma unroll
    for (int nt = 0; nt < 4; ++nt)
        bp[nt] = w1t + (size_t)(col_base + nt * 16 + c) * IN_FEAT + quad * 8;

#pragma unroll
    for (int k0 = 0; k0 < IN_FEAT; k0 += 32) {
        short8 a[2], b[4];
#pragma unroll
        for (int rt = 0; rt < 2; ++rt) {
            float4 f0 = *(const float4*)(xp[rt] + k0);
            float4 f1 = *(const float4*)(xp[rt] + k0 + 4);
            union { short8 s; unsigned u[4]; } au;
            au.u[0] = pk2bf(f0.x, f0.y);
            au.u[1] = pk2bf(f0.z, f0.w);
            au.u[2] = pk2bf(f1.x, f1.y);
            au.u[3] = pk2bf(f1.z, f1.w);
            a[rt] = au.s;
        }
#pragma unroll
        for (int nt = 0; nt < 4; ++nt)
            b[nt] = *(const short8*)(bp[nt] + k0);
#pragma unroll
        for (int rt = 0; rt < 2; ++rt)
#pragma unroll
            for (int nt = 0; nt < 4; ++nt)
                acc[rt][nt] = __builtin_amdgcn_mfma_f32_16x16x32_bf16(a[rt], b[nt], acc[rt][nt], 0, 0, 0);
    }

    // Epilogue: dis scale, pair adjacent cols via shfl, pack bf16x2, store.
    // C/D layout (verified m89/m91): col = lane&15, row = quad*4 + reg.
    bool evenlane = (lane & 1) == 0;
#pragma unroll
    for (int rt = 0; rt < 2; ++rt) {
#pragma unroll
        for (int reg = 0; reg < 4; ++reg) {
            int row = row_base + rt * 16 + quad * 4 + reg;
            float dv = dis[min(row, N_NODES - 1)];
#pragma unroll
            for (int nt = 0; nt < 4; ++nt) {
                float v = acc[rt][nt][reg] * dv;
                float vo = __shfl_xor(v, 1);
                if (evenlane && row < N_NODES) {
                    unsigned pkd = (unsigned)f2bf(v) | ((unsigned)f2bf(vo) << 16);
                    g1[(size_t)row * 64 + (col_base >> 1) + nt * 8 + (c >> 1)] = pkd;
                }
            }
        }
    }
}

// ---------------------------------------------------------------------------
// Fused: aggregation 1 + bias + ReLU + GEMM2 (+dis scale).
// One wave per node; g1 rows are bf16x2 per lane (256B/row), unroll 8.
// ---------------------------------------------------------------------------
__global__ __launch_bounds__(256) void agg1_gemm2(const unsigned int* __restrict__ g1,
                                                  const int* __restrict__ row_start,
                                                  const unsigned short* __restrict__ csr_src,
                                                  const float* __restrict__ dis,
                                                  const float* __restrict__ b1,
                                                  const float* __restrict__ W2,
                                                  float* __restrict__ g2) {
    __shared__ float w2s[HIDDEN * N_CLASSES];   // 8 KB
    __shared__ float rs[4][HIDDEN];             // 2 KB, per-wave regions
    int tid = threadIdx.x;
    for (int i = tid; i < HIDDEN * N_CLASSES; i += 256) w2s[i] = W2[i];
    __syncthreads();

    int wave = tid >> 6;
    int lane = tid & 63;
    int node = blockIdx.x * 4 + wave;  // 12500*4 == 50000

    unsigned su = g1[(size_t)node * 64 + lane];  // self loop term
    float a0x = __uint_as_float(su << 16), a0y = __uint_as_float(su & 0xffff0000u);
    float a1x = 0.f, a1y = 0.f, a2x = 0.f, a2y = 0.f, a3x = 0.f, a3y = 0.f;
    float a4x = 0.f, a4y = 0.f, a5x = 0.f, a5y = 0.f, a6x = 0.f, a6y = 0.f, a7x = 0.f, a7y = 0.f;

    int e0 = row_start[node], e1 = row_start[node + 1];
    int e = e0;
    for (; e + 8 <= e1; e += 8) {
        int s0 = csr_src[e + 0], s1 = csr_src[e + 1], s2 = csr_src[e + 2], s3 = csr_src[e + 3];
        int s4 = csr_src[e + 4], s5 = csr_src[e + 5], s6 = csr_src[e + 6], s7 = csr_src[e + 7];
        unsigned u0 = g1[(size_t)s0 * 64 + lane];
        unsigned u1 = g1[(size_t)s1 * 64 + lane];
        unsigned u2 = g1[(size_t)s2 * 64 + lane];
        unsigned u3 = g1[(size_t)s3 * 64 + lane];
        unsigned u4 = g1[(size_t)s4 * 64 + lane];
        unsigned u5 = g1[(size_t)s5 * 64 + lane];
        unsigned u6 = g1[(size_t)s6 * 64 + lane];
        unsigned u7 = g1[(size_t)s7 * 64 + lane];
        a0x += __uint_as_float(u0 << 16); a0y += __uint_as_float(u0 & 0xffff0000u);
        a1x += __uint_as_float(u1 << 16); a1y += __uint_as_float(u1 & 0xffff0000u);
        a2x += __uint_as_float(u2 << 16); a2y += __uint_as_float(u2 & 0xffff0000u);
        a3x += __uint_as_float(u3 << 16); a3y += __uint_as_float(u3 & 0xffff0000u);
        a4x += __uint_as_float(u4 << 16); a4y += __uint_as_float(u4 & 0xffff0000u);
        a5x += __uint_as_float(u5 << 16); a5y += __uint_as_float(u5 & 0xffff0000u);
        a6x += __uint_as_float(u6 << 16); a6y += __uint_as_float(u6 & 0xffff0000u);
        a7x += __uint_as_float(u7 << 16); a7y += __uint_as_float(u7 & 0xffff0000u);
    }
    for (; e < e1; ++e) {
        int s = csr_src[e];
        unsigned u = g1[(size_t)s * 64 + lane];
        a0x += __uint_as_float(u << 16); a0y += __uint_as_float(u & 0xffff0000u);
    }
    float sx = ((a0x + a1x) + (a2x + a3x)) + ((a4x + a5x) + (a6x + a7x));
    float sy = ((a0y + a1y) + (a2y + a3y)) + ((a4y + a5y) + (a6y + a7y));

    float dv = dis[node];
    float2 bb = ((const float2*)b1)[lane];
    float rx = fmaxf(fmaf(dv, sx, bb.x), 0.f);
    float ry = fmaxf(fmaf(dv, sy, bb.y), 0.f);

    *(float2*)&rs[wave][lane * 2] = make_float2(rx, ry);

    int grp = lane >> 4;
    int c = lane & 15;
    int f0 = grp * 32;
    float p = 0.f;
#pragma unroll
    for (int k = 0; k < 32; ++k)
        p = fmaf(rs[wave][f0 + k], w2s[(f0 + k) * N_CLASSES + c], p);
    p += __shfl_xor(p, 16);
    p += __shfl_xor(p, 32);
    if (lane < 16) g2[(size_t)node * N_CLASSES + lane] = dv * p;
}

// ---------------------------------------------------------------------------
// Aggregation 2 + bias + logits + softmax. 16 lanes per node, unroll 8.
// ---------------------------------------------------------------------------
__global__ __launch_bounds__(256) void agg2_softmax(const float* __restrict__ g2,
                                                    const int* __restrict__ row_start,
                                                    const unsigned short* __restrict__ csr_src,
                                                    const float* __restrict__ dis,
                                                    const float* __restrict__ b2,
                                                    float* __restrict__ out) {
    int tid = threadIdx.x;
    int node = blockIdx.x * 16 + (tid >> 4);
    int c = tid & 15;
    float acc0 = g2[(size_t)node * N_CLASSES + c];
    float acc1 = 0.f, acc2 = 0.f, acc3 = 0.f;
    float acc4 = 0.f, acc5 = 0.f, acc6 = 0.f, acc7 = 0.f;
    int e0 = row_start[node], e1 = row_start[node + 1];
    int e = e0;
    for (; e + 8 <= e1; e += 8) {
        int s0 = csr_src[e + 0], s1 = csr_src[e + 1], s2 = csr_src[e + 2], s3 = csr_src[e + 3];
        int s4 = csr_src[e + 4], s5 = csr_src[e + 5], s6 = csr_src[e + 6], s7 = csr_src[e + 7];
        acc0 += g2[(size_t)s0 * N_CLASSES + c];
        acc1 += g2[(size_t)s1 * N_CLASSES + c];
        acc2 += g2[(size_t)s2 * N_CLASSES + c];
        acc3 += g2[(size_t)s3 * N_CLASSES + c];
        acc4 += g2[(size_t)s4 * N_CLASSES + c];
        acc5 += g2[(size_t)s5 * N_CLASSES + c];
        acc6 += g2[(size_t)s6 * N_CLASSES + c];
        acc7 += g2[(size_t)s7 * N_CLASSES + c];
    }
    for (; e < e1; ++e) {
        int s = csr_src[e];
        acc0 += g2[(size_t)s * N_CLASSES + c];
    }
    acc0 = ((acc0 + acc1) + (acc2 + acc3)) + ((acc4 + acc5) + (acc6 + acc7));
    float logit = fmaf(dis[node], acc0, b2[c]);
    out[(size_t)node * N_CLASSES + c] = logit;
    float m = logit;
    for (int off = 8; off; off >>= 1) m = fmaxf(m, __shfl_xor(m, off));
    float ex = expf(logit - m);
    float s = ex;
    for (int off = 8; off; off >>= 1) s += __shfl_xor(s, off);
    out[(size_t)N_NODES * N_CLASSES + (size_t)node * N_CLASSES + c] = ex / s;
}

// ---------------------------------------------------------------------------

extern "C" void kernel_launch(void* const* d_in, const int* in_sizes, int n_in,
                              void* d_out, int out_size, void* d_ws, size_t ws_size,
                              hipStream_t stream) {
    const float* x  = (const float*)d_in[0];
    const int*   ei = (const int*)d_in[1];
    const float* W1 = (const float*)d_in[2];
    const float* b1 = (const float*)d_in[3];
    const float* W2 = (const float*)d_in[4];
    const float* b2 = (const float*)d_in[5];
    float* out = (float*)d_out;

    char* ws = (char*)d_ws;
    size_t off = 0;
    auto alloc = [&](size_t bytes) -> char* {
        char* p = ws + off;
        off = (off + bytes + 511) & ~(size_t)511;
        return p;
    };
    int*   hist        = (int*)alloc((size_t)NCHK * 256 * 4);
    int*   bucket_base = (int*)alloc(256 * 4);
    float* dis         = (float*)alloc(N_NODES * 4);
    int*   row_start   = (int*)alloc((N_NODES + 1) * 4);
    unsigned short* w1t = (unsigned short*)alloc((size_t)HIDDEN * IN_FEAT * 2);  // bf16 [n][k]
    unsigned short* csr_src = (unsigned short*)alloc((size_t)N_EDGES * 2);
    unsigned int* g1   = (unsigned int*)alloc((size_t)N_NODES * 64 * 4);  // bf16x2 per lane
    float* g2          = (float*)alloc((size_t)N_NODES * N_CLASSES * 4);
    // sorted edge array (6.4MB) aliases g1's slab: dead before gemm1 writes g1.
    unsigned int* sorted = (unsigned int*)g1;
    (void)ws_size; (void)in_sizes; (void)n_in; (void)out_size;

    const int* src = ei;
    const int* dst = ei + N_EDGES;

    edge_hist<<<NCHK, 256, 0, stream>>>(dst, hist, W1, w1t);
    scan_hist<<<1, 256, 0, stream>>>(hist, bucket_base);
    scatter_edges<<<NCHK, 256, 0, stream>>>(src, dst, hist, sorted);
    build_csr<<<NBKT, 256, 0, stream>>>(sorted, bucket_base, row_start, dis, csr_src);

    gemm1_mfma<<<(N_NODES + 63) / 64, 256, 0, stream>>>(x, w1t, dis, g1);
    agg1_gemm2<<<N_NODES / 4, 256, 0, stream>>>(g1, row_start, csr_src, dis, b1, W2, g2);
    agg2_softmax<<<N_NODES / 16, 256, 0, stream>>>(g2, row_start, csr_src, dis, b2, out);
}

// Round 7
// 249.282 us; speedup vs baseline: 2.2178x; 1.0415x over previous
//
#include <hip/hip_runtime.h>
#include <hip/hip_bf16.h>
#include <math.h>

#define N_NODES 50000
#define N_EDGES 1600000
#define IN_FEAT 256
#define HIDDEN 128
#define N_CLASSES 16

#define ECHUNK 8192
#define NCHK 196    // ceil(1600000/8192)
#define NBKT 196    // ceil(50000/256) buckets of 256 nodes
#define BCAP 10240  // per-bucket capacity: mean 8192, std ~90 -> +23 sigma

typedef __attribute__((ext_vector_type(8))) short short8;   // 8 bf16 (A/B frag)
typedef __attribute__((ext_vector_type(4))) float floatx4;  // C/D frag

// bf16 round-to-nearest-even (scalar integer path)
__device__ __forceinline__ unsigned short f2bf(float f) {
    unsigned u = __float_as_uint(f);
    return (unsigned short)((u + 0x7fffu + ((u >> 16) & 1u)) >> 16);
}

// HW packed fp32->bf16x2
__device__ __forceinline__ unsigned pk2bf(float a, float b) {
    __hip_bfloat162 h = __float22bfloat162_rn(make_float2(a, b));
    union { __hip_bfloat162 h; unsigned u; } cv;
    cv.h = h;
    return cv.u;
}

// ---------------------------------------------------------------------------
// Prep v3: fixed-capacity buckets, no global hist/scan.
// scatter_edges2: LDS-count -> 1 global atomic per (block,bucket) -> 2nd pass
// local scatter. Blocks 0..127 also transpose W1 -> bf16 w1t[n][k].
// ---------------------------------------------------------------------------
__global__ __launch_bounds__(256) void scatter_edges2(const int* __restrict__ src,
                                                      const int* __restrict__ dst,
                                                      int* __restrict__ cursor,   // [256], zeroed
                                                      unsigned int* __restrict__ sorted,
                                                      const float* __restrict__ W1,
                                                      unsigned short* __restrict__ w1t) {
    __shared__ int hloc[256];
    int t = threadIdx.x;
    hloc[t] = 0;
    if (blockIdx.x < HIDDEN)
        w1t[blockIdx.x * IN_FEAT + t] = f2bf(W1[t * HIDDEN + blockIdx.x]);
    __syncthreads();
    int base = blockIdx.x * ECHUNK;
    int end = min(base + ECHUNK, N_EDGES);
    for (int i = base + t; i < end; i += 256)
        atomicAdd(&hloc[dst[i] >> 8], 1);
    __syncthreads();
    int cnt = hloc[t];
    int lbase = t * BCAP + atomicAdd(&cursor[t], cnt);  // block's base in bucket t
    __syncthreads();
    hloc[t] = lbase;  // reuse as local cursor
    __syncthreads();
    for (int i = base + t; i < end; i += 256) {
        int d = dst[i];
        int s = src[i];
        int pos = atomicAdd(&hloc[d >> 8], 1);
        sorted[pos] = ((unsigned)d << 16) | (unsigned)s;
    }
}

// build_csr2: one block per bucket; per-node [rs,re) + dis + local csr fill.
__global__ __launch_bounds__(256) void build_csr2(const unsigned int* __restrict__ sorted,
                                                  const int* __restrict__ cursor,
                                                  int* __restrict__ rs,
                                                  int* __restrict__ re,
                                                  float* __restrict__ dis,
                                                  unsigned short* __restrict__ csr_src) {
    __shared__ int cnt[256];
    __shared__ int roff[256];
    int t = threadIdx.x;
    int bkt = blockIdx.x;
    int ebase = bkt * BCAP;
    int eend = ebase + cursor[bkt];
    cnt[t] = 0;
    __syncthreads();
    for (int i = ebase + t; i < eend; i += 256)
        atomicAdd(&cnt[(sorted[i] >> 16) & 255], 1);
    __syncthreads();
    int v = cnt[t];
    roff[t] = v;
    __syncthreads();
    for (int off = 1; off < 256; off <<= 1) {
        int x = (t >= off) ? roff[t - off] : 0;
        __syncthreads();
        roff[t] += x;
        __syncthreads();
    }
    int excl = roff[t] - v;
    int node = bkt * 256 + t;
    if (node < N_NODES) {
        rs[node] = ebase + excl;
        re[node] = ebase + excl + v;
        dis[node] = 1.0f / sqrtf((float)(v + 1));  // +1 self loop
    }
    __syncthreads();
    cnt[t] = ebase + excl;  // reuse as cursor
    __syncthreads();
    for (int i = ebase + t; i < eend; i += 256) {
        unsigned e = sorted[i];
        int pos = atomicAdd(&cnt[(e >> 16) & 255], 1);
        csr_src[pos] = (unsigned short)(e & 0xffffu);
    }
}

// ---------------------------------------------------------------------------
// GEMM1 via MFMA, register double-buffered K-loop:
// issue k0+32 loads (A raw fp32 + B bf16) BEFORE k0's MFMAs -> one k-step of
// latency tolerance per wave. Block 64 rows x 128 cols, wave 32x64.
// ---------------------------------------------------------------------------
__global__ __launch_bounds__(256) void gemm1_mfma(const float* __restrict__ x,
                                                  const unsigned short* __restrict__ w1t,
                                                  const float* __restrict__ dis,
                                                  unsigned int* __restrict__ g1) {
    int tid = threadIdx.x;
    int w = tid >> 6;
    int lane = tid & 63;
    int quad = lane >> 4;
    int c = lane & 15;
    int row_base = blockIdx.x * 64 + (w >> 1) * 32;
    int col_base = (w & 1) * 64;

    floatx4 acc[2][4] = {};

    const float* xp[2];
#pragma unroll
    for (int rt = 0; rt < 2; ++rt) {
        int r = min(row_base + rt * 16 + c, N_NODES - 1);
        xp[rt] = x + (size_t)r * IN_FEAT + quad * 8;
    }
    const unsigned short* bp[4];
#pragma unroll
    for (int nt = 0; nt < 4; ++nt)
        bp[nt] = w1t + (size_t)(col_base + nt * 16 + c) * IN_FEAT + quad * 8;

    float4 fa[2][2];
    short8 bcur[4];
#pragma unroll
    for (int rt = 0; rt < 2; ++rt) {
        fa[rt][0] = *(const float4*)(xp[rt] + 0);
        fa[rt][1] = *(const float4*)(xp[rt] + 4);
    }
#pragma unroll
    for (int nt = 0; nt < 4; ++nt)
        bcur[nt] = *(const short8*)(bp[nt] + 0);

#pragma unroll
    for (int kk = 0; kk < 8; ++kk) {
        // prefetch next k-step (raw) before consuming current
        float4 fn[2][2];
        short8 bn[4];
        if (kk < 7) {
            int k0n = (kk + 1) * 32;
#pragma unroll
            for (int rt = 0; rt < 2; ++rt) {
                fn[rt][0] = *(const float4*)(xp[rt] + k0n);
                fn[rt][1] = *(const float4*)(xp[rt] + k0n + 4);
            }
#pragma unroll
            for (int nt = 0; nt < 4; ++nt)
                bn[nt] = *(const short8*)(bp[nt] + k0n);
        }
        // convert current A to bf16 and issue MFMAs
        short8 a[2];
#pragma unroll
        for (int rt = 0; rt < 2; ++rt) {
            union { short8 s; unsigned u[4]; } au;
            au.u[0] = pk2bf(fa[rt][0].x, fa[rt][0].y);
            au.u[1] = pk2bf(fa[rt][0].z, fa[rt][0].w);
            au.u[2] = pk2bf(fa[rt][1].x, fa[rt][1].y);
            au.u[3] = pk2bf(fa[rt][1].z, fa[rt][1].w);
            a[rt] = au.s;
        }
#pragma unroll
        for (int rt = 0; rt < 2; ++rt)
#pragma unroll
            for (int nt = 0; nt < 4; ++nt)
                acc[rt][nt] = __builtin_amdgcn_mfma_f32_16x16x32_bf16(a[rt], bcur[nt], acc[rt][nt], 0, 0, 0);
        if (kk < 7) {
#pragma unroll
            for (int rt = 0; rt < 2; ++rt) { fa[rt][0] = fn[rt][0]; fa[rt][1] = fn[rt][1]; }
#pragma unroll
            for (int nt = 0; nt < 4; ++nt) bcur[nt] = bn[nt];
        }
    }

    // Epilogue: dis scale, pair adjacent cols via shfl, pack bf16x2, store.
    // C/D layout: col = lane&15, row = quad*4 + reg.
    bool evenlane = (lane & 1) == 0;
#pragma unroll
    for (int rt = 0; rt < 2; ++rt) {
#pragma unroll
        for (int reg = 0; reg < 4; ++reg) {
            int row = row_base + rt * 16 + quad * 4 + reg;
            float dv = dis[min(row, N_NODES - 1)];
#pragma unroll
            for (int nt = 0; nt < 4; ++nt) {
                float v = acc[rt][nt][reg] * dv;
                float vo = __shfl_xor(v, 1);
                if (evenlane && row < N_NODES) {
                    unsigned pkd = (unsigned)f2bf(v) | ((unsigned)f2bf(vo) << 16);
                    g1[(size_t)row * 64 + (col_base >> 1) + nt * 8 + (c >> 1)] = pkd;
                }
            }
        }
    }
}

// ---------------------------------------------------------------------------
// Fused: aggregation 1 + bias + ReLU + GEMM2 (+dis scale).
// One wave per node; g1 rows bf16x2/lane (256B/row), unroll 8.
// ---------------------------------------------------------------------------
__global__ __launch_bounds__(256) void agg1_gemm2(const unsigned int* __restrict__ g1,
                                                  const int* __restrict__ rs,
                                                  const int* __restrict__ re,
                                                  const unsigned short* __restrict__ csr_src,
                                                  const float* __restrict__ dis,
                                                  const float* __restrict__ b1,
                                                  const float* __restrict__ W2,
                                                  float* __restrict__ g2) {
    __shared__ float w2s[HIDDEN * N_CLASSES];   // 8 KB
    __shared__ float rsh[4][HIDDEN];            // 2 KB, per-wave regions
    int tid = threadIdx.x;
    for (int i = tid; i < HIDDEN * N_CLASSES; i += 256) w2s[i] = W2[i];
    __syncthreads();

    int wave = tid >> 6;
    int lane = tid & 63;
    int node = blockIdx.x * 4 + wave;  // 12500*4 == 50000

    unsigned su = g1[(size_t)node * 64 + lane];  // self loop term
    float a0x = __uint_as_float(su << 16), a0y = __uint_as_float(su & 0xffff0000u);
    float a1x = 0.f, a1y = 0.f, a2x = 0.f, a2y = 0.f, a3x = 0.f, a3y = 0.f;
    float a4x = 0.f, a4y = 0.f, a5x = 0.f, a5y = 0.f, a6x = 0.f, a6y = 0.f, a7x = 0.f, a7y = 0.f;

    int e0 = rs[node], e1 = re[node];
    int e = e0;
    for (; e + 8 <= e1; e += 8) {
        int s0 = csr_src[e + 0], s1 = csr_src[e + 1], s2 = csr_src[e + 2], s3 = csr_src[e + 3];
        int s4 = csr_src[e + 4], s5 = csr_src[e + 5], s6 = csr_src[e + 6], s7 = csr_src[e + 7];
        unsigned u0 = g1[(size_t)s0 * 64 + lane];
        unsigned u1 = g1[(size_t)s1 * 64 + lane];
        unsigned u2 = g1[(size_t)s2 * 64 + lane];
        unsigned u3 = g1[(size_t)s3 * 64 + lane];
        unsigned u4 = g1[(size_t)s4 * 64 + lane];
        unsigned u5 = g1[(size_t)s5 * 64 + lane];
        unsigned u6 = g1[(size_t)s6 * 64 + lane];
        unsigned u7 = g1[(size_t)s7 * 64 + lane];
        a0x += __uint_as_float(u0 << 16); a0y += __uint_as_float(u0 & 0xffff0000u);
        a1x += __uint_as_float(u1 << 16); a1y += __uint_as_float(u1 & 0xffff0000u);
        a2x += __uint_as_float(u2 << 16); a2y += __uint_as_float(u2 & 0xffff0000u);
        a3x += __uint_as_float(u3 << 16); a3y += __uint_as_float(u3 & 0xffff0000u);
        a4x += __uint_as_float(u4 << 16); a4y += __uint_as_float(u4 & 0xffff0000u);
        a5x += __uint_as_float(u5 << 16); a5y += __uint_as_float(u5 & 0xffff0000u);
        a6x += __uint_as_float(u6 << 16); a6y += __uint_as_float(u6 & 0xffff0000u);
        a7x += __uint_as_float(u7 << 16); a7y += __uint_as_float(u7 & 0xffff0000u);
    }
    for (; e < e1; ++e) {
        int s = csr_src[e];
        unsigned u = g1[(size_t)s * 64 + lane];
        a0x += __uint_as_float(u << 16); a0y += __uint_as_float(u & 0xffff0000u);
    }
    float sx = ((a0x + a1x) + (a2x + a3x)) + ((a4x + a5x) + (a6x + a7x));
    float sy = ((a0y + a1y) + (a2y + a3y)) + ((a4y + a5y) + (a6y + a7y));

    float dv = dis[node];
    float2 bb = ((const float2*)b1)[lane];
    float rx = fmaxf(fmaf(dv, sx, bb.x), 0.f);
    float ry = fmaxf(fmaf(dv, sy, bb.y), 0.f);

    *(float2*)&rsh[wave][lane * 2] = make_float2(rx, ry);

    int grp = lane >> 4;
    int c = lane & 15;
    int f0 = grp * 32;
    float p = 0.f;
#pragma unroll
    for (int k = 0; k < 32; ++k)
        p = fmaf(rsh[wave][f0 + k], w2s[(f0 + k) * N_CLASSES + c], p);
    p += __shfl_xor(p, 16);
    p += __shfl_xor(p, 32);
    if (lane < 16) g2[(size_t)node * N_CLASSES + lane] = dv * p;
}

// ---------------------------------------------------------------------------
// Aggregation 2 + bias + logits + softmax. 16 lanes per node, unroll 8.
// ---------------------------------------------------------------------------
__global__ __launch_bounds__(256) void agg2_softmax(const float* __restrict__ g2,
                                                    const int* __restrict__ rs,
                                                    const int* __restrict__ re,
                                                    const unsigned short* __restrict__ csr_src,
                                                    const float* __restrict__ dis,
                                                    const float* __restrict__ b2,
                                                    float* __restrict__ out) {
    int tid = threadIdx.x;
    int node = blockIdx.x * 16 + (tid >> 4);
    int c = tid & 15;
    float acc0 = g2[(size_t)node * N_CLASSES + c];
    float acc1 = 0.f, acc2 = 0.f, acc3 = 0.f;
    float acc4 = 0.f, acc5 = 0.f, acc6 = 0.f, acc7 = 0.f;
    int e0 = rs[node], e1 = re[node];
    int e = e0;
    for (; e + 8 <= e1; e += 8) {
        int s0 = csr_src[e + 0], s1 = csr_src[e + 1], s2 = csr_src[e + 2], s3 = csr_src[e + 3];
        int s4 = csr_src[e + 4], s5 = csr_src[e + 5], s6 = csr_src[e + 6], s7 = csr_src[e + 7];
        acc0 += g2[(size_t)s0 * N_CLASSES + c];
        acc1 += g2[(size_t)s1 * N_CLASSES + c];
        acc2 += g2[(size_t)s2 * N_CLASSES + c];
        acc3 += g2[(size_t)s3 * N_CLASSES + c];
        acc4 += g2[(size_t)s4 * N_CLASSES + c];
        acc5 += g2[(size_t)s5 * N_CLASSES + c];
        acc6 += g2[(size_t)s6 * N_CLASSES + c];
        acc7 += g2[(size_t)s7 * N_CLASSES + c];
    }
    for (; e < e1; ++e) {
        int s = csr_src[e];
        acc0 += g2[(size_t)s * N_CLASSES + c];
    }
    acc0 = ((acc0 + acc1) + (acc2 + acc3)) + ((acc4 + acc5) + (acc6 + acc7));
    float logit = fmaf(dis[node], acc0, b2[c]);
    out[(size_t)node * N_CLASSES + c] = logit;
    float m = logit;
    for (int off = 8; off; off >>= 1) m = fmaxf(m, __shfl_xor(m, off));
    float ex = expf(logit - m);
    float s = ex;
    for (int off = 8; off; off >>= 1) s += __shfl_xor(s, off);
    out[(size_t)N_NODES * N_CLASSES + (size_t)node * N_CLASSES + c] = ex / s;
}

// ---------------------------------------------------------------------------

extern "C" void kernel_launch(void* const* d_in, const int* in_sizes, int n_in,
                              void* d_out, int out_size, void* d_ws, size_t ws_size,
                              hipStream_t stream) {
    const float* x  = (const float*)d_in[0];
    const int*   ei = (const int*)d_in[1];
    const float* W1 = (const float*)d_in[2];
    const float* b1 = (const float*)d_in[3];
    const float* W2 = (const float*)d_in[4];
    const float* b2 = (const float*)d_in[5];
    float* out = (float*)d_out;

    char* ws = (char*)d_ws;
    size_t off = 0;
    auto alloc = [&](size_t bytes) -> char* {
        char* p = ws + off;
        off = (off + bytes + 511) & ~(size_t)511;
        return p;
    };
    int*   cursor   = (int*)alloc(256 * 4);
    float* dis      = (float*)alloc(N_NODES * 4);
    int*   rs       = (int*)alloc(N_NODES * 4);
    int*   re       = (int*)alloc(N_NODES * 4);
    unsigned short* w1t = (unsigned short*)alloc((size_t)HIDDEN * IN_FEAT * 2);
    unsigned short* csr_src = (unsigned short*)alloc((size_t)NBKT * BCAP * 2);  // holey
    unsigned int* g1 = (unsigned int*)alloc((size_t)N_NODES * 64 * 4);          // bf16x2/lane
    float* g2       = (float*)alloc((size_t)N_NODES * N_CLASSES * 4);
    // sorted edges (196*10240*4 = 8.0MB) alias g1's slab (12.8MB): dead before gemm1.
    unsigned int* sorted = (unsigned int*)g1;
    (void)ws_size; (void)in_sizes; (void)n_in; (void)out_size;

    const int* src = ei;
    const int* dst = ei + N_EDGES;

    hipMemsetAsync(cursor, 0, 256 * 4, stream);
    scatter_edges2<<<NCHK, 256, 0, stream>>>(src, dst, cursor, sorted, W1, w1t);
    build_csr2<<<NBKT, 256, 0, stream>>>(sorted, cursor, rs, re, dis, csr_src);

    gemm1_mfma<<<(N_NODES + 63) / 64, 256, 0, stream>>>(x, w1t, dis, g1);
    agg1_gemm2<<<N_NODES / 4, 256, 0, stream>>>(g1, rs, re, csr_src, dis, b1, W2, g2);
    agg2_softmax<<<N_NODES / 16, 256, 0, stream>>>(g2, rs, re, csr_src, dis, b2, out);
}

// Round 8
// 240.729 us; speedup vs baseline: 2.2966x; 1.0355x over previous
//
#include <hip/hip_runtime.h>
#include <hip/hip_bf16.h>
#include <math.h>

#define N_NODES 50000
#define N_EDGES 1600000
#define IN_FEAT 256
#define HIDDEN 128
#define N_CLASSES 16

#define ECHUNK 8192
#define NCHK 196    // ceil(1600000/8192)
#define NBKT 196    // ceil(50000/256) buckets of 256 nodes
#define BCAP 10240  // per-bucket capacity: mean 8192, std ~90 -> +23 sigma

typedef __attribute__((ext_vector_type(8))) short short8;   // 8 bf16 (A/B frag)
typedef __attribute__((ext_vector_type(4))) float floatx4;  // C/D frag

// bf16 round-to-nearest-even (scalar integer path)
__device__ __forceinline__ unsigned short f2bf(float f) {
    unsigned u = __float_as_uint(f);
    return (unsigned short)((u + 0x7fffu + ((u >> 16) & 1u)) >> 16);
}

// HW packed fp32->bf16x2
__device__ __forceinline__ unsigned pk2bf(float a, float b) {
    __hip_bfloat162 h = __float22bfloat162_rn(make_float2(a, b));
    union { __hip_bfloat162 h; unsigned u; } cv;
    cv.h = h;
    return cv.u;
}

__device__ __forceinline__ float bflo(unsigned u) { return __uint_as_float(u << 16); }
__device__ __forceinline__ float bfhi(unsigned u) { return __uint_as_float(u & 0xffff0000u); }

// ---------------------------------------------------------------------------
// Prep: fixed-capacity buckets. scatter: LDS-count -> 1 global atomic per
// (block,bucket) -> local scatter. Blocks 0..127 also transpose W1 -> w1t.
// ---------------------------------------------------------------------------
__global__ __launch_bounds__(256) void scatter_edges2(const int* __restrict__ src,
                                                      const int* __restrict__ dst,
                                                      int* __restrict__ cursor,   // [256], zeroed
                                                      unsigned int* __restrict__ sorted,
                                                      const float* __restrict__ W1,
                                                      unsigned short* __restrict__ w1t) {
    __shared__ int hloc[256];
    int t = threadIdx.x;
    hloc[t] = 0;
    if (blockIdx.x < HIDDEN)
        w1t[blockIdx.x * IN_FEAT + t] = f2bf(W1[t * HIDDEN + blockIdx.x]);
    __syncthreads();
    int base = blockIdx.x * ECHUNK;
    int end = min(base + ECHUNK, N_EDGES);
    for (int i = base + t; i < end; i += 256)
        atomicAdd(&hloc[dst[i] >> 8], 1);
    __syncthreads();
    int cnt = hloc[t];
    int lbase = t * BCAP + atomicAdd(&cursor[t], cnt);  // block's base in bucket t
    __syncthreads();
    hloc[t] = lbase;  // reuse as local cursor
    __syncthreads();
    for (int i = base + t; i < end; i += 256) {
        int d = dst[i];
        int s = src[i];
        int pos = atomicAdd(&hloc[d >> 8], 1);
        sorted[pos] = ((unsigned)d << 16) | (unsigned)s;
    }
}

__global__ __launch_bounds__(256) void build_csr2(const unsigned int* __restrict__ sorted,
                                                  const int* __restrict__ cursor,
                                                  int* __restrict__ rs,
                                                  int* __restrict__ re,
                                                  float* __restrict__ dis,
                                                  unsigned short* __restrict__ csr_src) {
    __shared__ int cnt[256];
    __shared__ int roff[256];
    int t = threadIdx.x;
    int bkt = blockIdx.x;
    int ebase = bkt * BCAP;
    int eend = ebase + cursor[bkt];
    cnt[t] = 0;
    __syncthreads();
    for (int i = ebase + t; i < eend; i += 256)
        atomicAdd(&cnt[(sorted[i] >> 16) & 255], 1);
    __syncthreads();
    int v = cnt[t];
    roff[t] = v;
    __syncthreads();
    for (int off = 1; off < 256; off <<= 1) {
        int x = (t >= off) ? roff[t - off] : 0;
        __syncthreads();
        roff[t] += x;
        __syncthreads();
    }
    int excl = roff[t] - v;
    int node = bkt * 256 + t;
    if (node < N_NODES) {
        rs[node] = ebase + excl;
        re[node] = ebase + excl + v;
        dis[node] = 1.0f / sqrtf((float)(v + 1));  // +1 self loop
    }
    __syncthreads();
    cnt[t] = ebase + excl;  // reuse as cursor
    __syncthreads();
    for (int i = ebase + t; i < eend; i += 256) {
        unsigned e = sorted[i];
        int pos = atomicAdd(&cnt[(e >> 16) & 255], 1);
        csr_src[pos] = (unsigned short)(e & 0xffffu);
    }
}

// ---------------------------------------------------------------------------
// GEMM1 via MFMA with LDS-staged A (global_load_lds, width 16).
// Block 64 rows x 128 cols, 4 waves (2x2); wave = 32 rows x 64 cols.
// x-tile (64 rows x 32 k, fp32) staged coalesced: each 1KB issue covers
// 8 rows x 128 B contiguous (16 full lines). Chunk-padded LDS layout
// (260 dw per 8-row chunk) keeps ds_read_b128 at the 8-deep bank minimum.
// B (w1t, L2-resident) read direct from global: its pattern is already
// line-minimal (16-lane c-group x 4-quad span = 64 B contiguous).
// ---------------------------------------------------------------------------
#define XCH 260   // dwords per 8-row chunk: 8*32 + 4 pad

__global__ __launch_bounds__(256) void gemm1_mfma(const float* __restrict__ x,
                                                  const unsigned short* __restrict__ w1t,
                                                  const float* __restrict__ dis,
                                                  unsigned int* __restrict__ g1) {
    __shared__ float xs[2][8 * XCH];   // 2 x 8320 B
    int tid = threadIdx.x;
    int w = tid >> 6;
    int lane = tid & 63;
    int quad = lane >> 4;
    int c = lane & 15;
    int row_base = blockIdx.x * 64;
    int wrow = (w >> 1) * 32;        // wave's row offset in tile
    int col_base = (w & 1) * 64;

    // staging: wave w stages chunks 2w, 2w+1 (rows 16w..16w+15 of the tile)
    int st_row = min(row_base + 16 * w + (lane >> 3), N_NODES - 1);       // chunk 2w
    int st_row2 = min(row_base + 16 * w + 8 + (lane >> 3), N_NODES - 1);  // chunk 2w+1
    const float* gp1 = x + (size_t)st_row * IN_FEAT + (lane & 7) * 4;
    const float* gp2 = x + (size_t)st_row2 * IN_FEAT + (lane & 7) * 4;

    floatx4 acc[2][4] = {};
    const unsigned short* bp[4];
#pragma unroll
    for (int nt = 0; nt < 4; ++nt)
        bp[nt] = w1t + (size_t)(col_base + nt * 16 + c) * IN_FEAT + quad * 8;

    // A-frag ds_read offsets (dwords) for rt=0,1
    int dwoff[2];
#pragma unroll
    for (int rt = 0; rt < 2; ++rt) {
        int rit = wrow + rt * 16 + c;
        dwoff[rt] = (rit >> 3) * XCH + (rit & 7) * 32 + quad * 8;
    }

#define STAGE(buf, k0)                                                                  \
    do {                                                                                \
        __builtin_amdgcn_global_load_lds(                                               \
            (const __attribute__((address_space(1))) void*)(gp1 + (k0)),                \
            (__attribute__((address_space(3))) void*)&xs[buf][(2 * w) * XCH], 16, 0, 0);\
        __builtin_amdgcn_global_load_lds(                                               \
            (const __attribute__((address_space(1))) void*)(gp2 + (k0)),                \
            (__attribute__((address_space(3))) void*)&xs[buf][(2 * w + 1) * XCH], 16, 0, 0);\
    } while (0)

    STAGE(0, 0);
    __syncthreads();

    int buf = 0;
#pragma unroll
    for (int kk = 0; kk < 8; ++kk) {
        if (kk < 7) STAGE(buf ^ 1, (kk + 1) * 32);
        // B frags for this k-step (global, L2-hot)
        short8 b[4];
#pragma unroll
        for (int nt = 0; nt < 4; ++nt)
            b[nt] = *(const short8*)(bp[nt] + kk * 32);
        // A frags from LDS, convert fp32 -> bf16
        short8 a[2];
#pragma unroll
        for (int rt = 0; rt < 2; ++rt) {
            float4 f0 = *(const float4*)&xs[buf][dwoff[rt]];
            float4 f1 = *(const float4*)&xs[buf][dwoff[rt] + 4];
            union { short8 s; unsigned u[4]; } au;
            au.u[0] = pk2bf(f0.x, f0.y);
            au.u[1] = pk2bf(f0.z, f0.w);
            au.u[2] = pk2bf(f1.x, f1.y);
            au.u[3] = pk2bf(f1.z, f1.w);
            a[rt] = au.s;
        }
#pragma unroll
        for (int rt = 0; rt < 2; ++rt)
#pragma unroll
            for (int nt = 0; nt < 4; ++nt)
                acc[rt][nt] = __builtin_amdgcn_mfma_f32_16x16x32_bf16(a[rt], b[nt], acc[rt][nt], 0, 0, 0);
        __syncthreads();   // drains stage vmcnt + protects buf reuse
        buf ^= 1;
    }
#undef STAGE

    // Epilogue: dis scale, pair adjacent cols via shfl, pack bf16x2, store.
    // C/D layout: col = lane&15, row = quad*4 + reg.
    bool evenlane = (lane & 1) == 0;
#pragma unroll
    for (int rt = 0; rt < 2; ++rt) {
#pragma unroll
        for (int reg = 0; reg < 4; ++reg) {
            int row = row_base + wrow + rt * 16 + quad * 4 + reg;
            float dv = dis[min(row, N_NODES - 1)];
#pragma unroll
            for (int nt = 0; nt < 4; ++nt) {
                float v = acc[rt][nt][reg] * dv;
                float vo = __shfl_xor(v, 1);
                if (evenlane && row < N_NODES) {
                    unsigned pkd = (unsigned)f2bf(v) | ((unsigned)f2bf(vo) << 16);
                    g1[(size_t)row * 64 + (col_base >> 1) + nt * 8 + (c >> 1)] = pkd;
                }
            }
        }
    }
}

// ---------------------------------------------------------------------------
// Fused: aggregation 1 + bias + ReLU + GEMM2 (+dis scale).
// Half-wave pair gather: 32 lanes x dwordx2 per row, 2 edges per wave-iter,
// unroll 8 pairs (16 edges, 4KB in flight/wave). Halves combined by one
// shfl_xor(32). r lives only in LDS; g2[node][c] = dis*(r@W2)[c].
// ---------------------------------------------------------------------------
__global__ __launch_bounds__(256) void agg1_gemm2(const unsigned int* __restrict__ g1,
                                                  const int* __restrict__ rs,
                                                  const int* __restrict__ re,
                                                  const unsigned short* __restrict__ csr_src,
                                                  const float* __restrict__ dis,
                                                  const float* __restrict__ b1,
                                                  const float* __restrict__ W2,
                                                  float* __restrict__ g2) {
    __shared__ float w2s[HIDDEN * N_CLASSES];   // 8 KB
    __shared__ float rsh[4][HIDDEN];            // 2 KB, per-wave regions
    int tid = threadIdx.x;
    for (int i = tid; i < HIDDEN * N_CLASSES; i += 256) w2s[i] = W2[i];
    __syncthreads();

    int wave = tid >> 6;
    int lane = tid & 63;
    int hi = lane >> 5;   // which edge of the pair this half-wave handles
    int m = lane & 31;    // feature quad: f = 4m..4m+3
    int node = blockIdx.x * 4 + wave;  // 12500*4 == 50000
    const uint2* g = (const uint2*)g1; // row = 32 x uint2 (8B, 4 feats)

    float s0 = 0.f, s1 = 0.f, s2 = 0.f, s3 = 0.f;
    float t0 = 0.f, t1 = 0.f, t2 = 0.f, t3 = 0.f;
    if (hi == 0) {  // self-loop counted once
        uint2 su = g[(size_t)node * 32 + m];
        s0 = bflo(su.x); s1 = bfhi(su.x); s2 = bflo(su.y); s3 = bfhi(su.y);
    }

    int e0 = rs[node], e1 = re[node];
    int e = e0;
    for (; e + 16 <= e1; e += 16) {
        int i0 = csr_src[e + 0 + hi], i1 = csr_src[e + 2 + hi];
        int i2 = csr_src[e + 4 + hi], i3 = csr_src[e + 6 + hi];
        int i4 = csr_src[e + 8 + hi], i5 = csr_src[e + 10 + hi];
        int i6 = csr_src[e + 12 + hi], i7 = csr_src[e + 14 + hi];
        uint2 u0 = g[(size_t)i0 * 32 + m];
        uint2 u1 = g[(size_t)i1 * 32 + m];
        uint2 u2 = g[(size_t)i2 * 32 + m];
        uint2 u3 = g[(size_t)i3 * 32 + m];
        uint2 u4 = g[(size_t)i4 * 32 + m];
        uint2 u5 = g[(size_t)i5 * 32 + m];
        uint2 u6 = g[(size_t)i6 * 32 + m];
        uint2 u7 = g[(size_t)i7 * 32 + m];
        s0 += bflo(u0.x); s1 += bfhi(u0.x); s2 += bflo(u0.y); s3 += bfhi(u0.y);
        t0 += bflo(u1.x); t1 += bfhi(u1.x); t2 += bflo(u1.y); t3 += bfhi(u1.y);
        s0 += bflo(u2.x); s1 += bfhi(u2.x); s2 += bflo(u2.y); s3 += bfhi(u2.y);
        t0 += bflo(u3.x); t1 += bfhi(u3.x); t2 += bflo(u3.y); t3 += bfhi(u3.y);
        s0 += bflo(u4.x); s1 += bfhi(u4.x); s2 += bflo(u4.y); s3 += bfhi(u4.y);
        t0 += bflo(u5.x); t1 += bfhi(u5.x); t2 += bflo(u5.y); t3 += bfhi(u5.y);
        s0 += bflo(u6.x); s1 += bfhi(u6.x); s2 += bflo(u6.y); s3 += bfhi(u6.y);
        t0 += bflo(u7.x); t1 += bfhi(u7.x); t2 += bflo(u7.y); t3 += bfhi(u7.y);
    }
    for (; e + 2 <= e1; e += 2) {
        int i0 = csr_src[e + hi];
        uint2 u = g[(size_t)i0 * 32 + m];
        s0 += bflo(u.x); s1 += bfhi(u.x); s2 += bflo(u.y); s3 += bfhi(u.y);
    }
    if (e < e1 && hi == 0) {  // odd leftover edge: hi=0 half only
        int i0 = csr_src[e];
        uint2 u = g[(size_t)i0 * 32 + m];
        s0 += bflo(u.x); s1 += bfhi(u.x); s2 += bflo(u.y); s3 += bfhi(u.y);
    }
    s0 += t0; s1 += t1; s2 += t2; s3 += t3;
    // combine the two half-wave edge streams (lane m <- lane m+32)
    s0 += __shfl_xor(s0, 32);
    s1 += __shfl_xor(s1, 32);
    s2 += __shfl_xor(s2, 32);
    s3 += __shfl_xor(s3, 32);

    float dv = dis[node];
    if (hi == 0) {
        float4 bb = *(const float4*)&b1[4 * m];
        float4 r;
        r.x = fmaxf(fmaf(dv, s0, bb.x), 0.f);
        r.y = fmaxf(fmaf(dv, s1, bb.y), 0.f);
        r.z = fmaxf(fmaf(dv, s2, bb.z), 0.f);
        r.w = fmaxf(fmaf(dv, s3, bb.w), 0.f);
        *(float4*)&rsh[wave][4 * m] = r;
    }

    // GEMM2: 4 lane-groups x 32 feats x 16 classes, shuffle-reduce
    int grp = lane >> 4;
    int c = lane & 15;
    int f0 = grp * 32;
    float p = 0.f;
#pragma unroll
    for (int k = 0; k < 32; ++k)
        p = fmaf(rsh[wave][f0 + k], w2s[(f0 + k) * N_CLASSES + c], p);
    p += __shfl_xor(p, 16);
    p += __shfl_xor(p, 32);
    if (lane < 16) g2[(size_t)node * N_CLASSES + lane] = dv * p;
}

// ---------------------------------------------------------------------------
// Aggregation 2 + bias + logits + softmax. 16 lanes per node, unroll 8.
// ---------------------------------------------------------------------------
__global__ __launch_bounds__(256) void agg2_softmax(const float* __restrict__ g2,
                                                    const int* __restrict__ rs,
                                                    const int* __restrict__ re,
                                                    const unsigned short* __restrict__ csr_src,
                                                    const float* __restrict__ dis,
                                                    const float* __restrict__ b2,
                                                    float* __restrict__ out) {
    int tid = threadIdx.x;
    int node = blockIdx.x * 16 + (tid >> 4);
    int c = tid & 15;
    float acc0 = g2[(size_t)node * N_CLASSES + c];
    float acc1 = 0.f, acc2 = 0.f, acc3 = 0.f;
    float acc4 = 0.f, acc5 = 0.f, acc6 = 0.f, acc7 = 0.f;
    int e0 = rs[node], e1 = re[node];
    int e = e0;
    for (; e + 8 <= e1; e += 8) {
        int s0 = csr_src[e + 0], s1 = csr_src[e + 1], s2 = csr_src[e + 2], s3 = csr_src[e + 3];
        int s4 = csr_src[e + 4], s5 = csr_src[e + 5], s6 = csr_src[e + 6], s7 = csr_src[e + 7];
        acc0 += g2[(size_t)s0 * N_CLASSES + c];
        acc1 += g2[(size_t)s1 * N_CLASSES + c];
        acc2 += g2[(size_t)s2 * N_CLASSES + c];
        acc3 += g2[(size_t)s3 * N_CLASSES + c];
        acc4 += g2[(size_t)s4 * N_CLASSES + c];
        acc5 += g2[(size_t)s5 * N_CLASSES + c];
        acc6 += g2[(size_t)s6 * N_CLASSES + c];
        acc7 += g2[(size_t)s7 * N_CLASSES + c];
    }
    for (; e < e1; ++e) {
        int s = csr_src[e];
        acc0 += g2[(size_t)s * N_CLASSES + c];
    }
    acc0 = ((acc0 + acc1) + (acc2 + acc3)) + ((acc4 + acc5) + (acc6 + acc7));
    float logit = fmaf(dis[node], acc0, b2[c]);
    out[(size_t)node * N_CLASSES + c] = logit;
    float m = logit;
    for (int off = 8; off; off >>= 1) m = fmaxf(m, __shfl_xor(m, off));
    float ex = expf(logit - m);
    float s = ex;
    for (int off = 8; off; off >>= 1) s += __shfl_xor(s, off);
    out[(size_t)N_NODES * N_CLASSES + (size_t)node * N_CLASSES + c] = ex / s;
}

// ---------------------------------------------------------------------------

extern "C" void kernel_launch(void* const* d_in, const int* in_sizes, int n_in,
                              void* d_out, int out_size, void* d_ws, size_t ws_size,
                              hipStream_t stream) {
    const float* x  = (const float*)d_in[0];
    const int*   ei = (const int*)d_in[1];
    const float* W1 = (const float*)d_in[2];
    const float* b1 = (const float*)d_in[3];
    const float* W2 = (const float*)d_in[4];
    const float* b2 = (const float*)d_in[5];
    float* out = (float*)d_out;

    char* ws = (char*)d_ws;
    size_t off = 0;
    auto alloc = [&](size_t bytes) -> char* {
        char* p = ws + off;
        off = (off + bytes + 511) & ~(size_t)511;
        return p;
    };
    int*   cursor   = (int*)alloc(256 * 4);
    float* dis      = (float*)alloc(N_NODES * 4);
    int*   rs       = (int*)alloc(N_NODES * 4);
    int*   re       = (int*)alloc(N_NODES * 4);
    unsigned short* w1t = (unsigned short*)alloc((size_t)HIDDEN * IN_FEAT * 2);
    unsigned short* csr_src = (unsigned short*)alloc((size_t)NBKT * BCAP * 2);  // holey
    unsigned int* g1 = (unsigned int*)alloc((size_t)N_NODES * 64 * 4);          // bf16x2/lane
    float* g2       = (float*)alloc((size_t)N_NODES * N_CLASSES * 4);
    // sorted edges (196*10240*4 = 8.0MB) alias g1's slab (12.8MB): dead before gemm1.
    unsigned int* sorted = (unsigned int*)g1;
    (void)ws_size; (void)in_sizes; (void)n_in; (void)out_size;

    const int* src = ei;
    const int* dst = ei + N_EDGES;

    hipMemsetAsync(cursor, 0, 256 * 4, stream);
    scatter_edges2<<<NCHK, 256, 0, stream>>>(src, dst, cursor, sorted, W1, w1t);
    build_csr2<<<NBKT, 256, 0, stream>>>(sorted, cursor, rs, re, dis, csr_src);

    gemm1_mfma<<<(N_NODES + 63) / 64, 256, 0, stream>>>(x, w1t, dis, g1);
    agg1_gemm2<<<N_NODES / 4, 256, 0, stream>>>(g1, rs, re, csr_src, dis, b1, W2, g2);
    agg2_softmax<<<N_NODES / 16, 256, 0, stream>>>(g2, rs, re, csr_src, dis, b2, out);
}